// Round 1
// baseline (582.753 us; speedup 1.0000x reference)
//
#include <hip/hip_runtime.h>

// ClassicalGCN: 2-layer GCN, N=40000, E=640000, 128 -> 128(relu) -> 64, f32.
// out_l = dinv ⊙ ( Âᵀ-aggregate( dinv ⊙ (x @ W) ) ) + b,  Â = A + I
// Pipeline: deg -> dinv -> [gemm+scale] -> [atomic scatter] -> fused epilogue+gemm2
//           -> scatter2 -> final bias.

#define N_NODES 40000
#define DIN 128
#define DH 128
#define DOUT 64
#define NEDGES 640000

// ---------------- degree / norm ----------------
__global__ void k_deg_init(int* __restrict__ deg, int n) {
    int i = blockIdx.x * 256 + threadIdx.x;
    if (i < n) deg[i] = 1;   // self-loop
}

__global__ void k_deg_accum(const int* __restrict__ dst, int* __restrict__ deg, int E) {
    int e = blockIdx.x * 256 + threadIdx.x;
    if (e < E) atomicAdd(&deg[dst[e]], 1);
}

__global__ void k_dinv(const int* __restrict__ deg, float* __restrict__ dinv, int n) {
    int i = blockIdx.x * 256 + threadIdx.x;
    if (i < n) dinv[i] = rsqrtf((float)deg[i]);   // deg >= 1 always (self-loop)
}

// ---------------- layer-1 GEMM:  h1 = dinv * (x @ W1); agg1 = h1 (self-loop) ----
// 32 rows/block, 256 threads; W1 staged in LDS in two 64-row halves (32KB),
// x tile 32x128 (16KB) -> 48KB LDS total.
__global__ __launch_bounds__(256) void k_gemm1(
    const float* __restrict__ x, const float* __restrict__ W,
    const float* __restrict__ dinv,
    float* __restrict__ h, float* __restrict__ agg)
{
    __shared__ float Wl[64 * DH];    // 32KB half of W1
    __shared__ float xs[32][DIN];    // 16KB
    const int row0 = blockIdx.x * 32;

    for (int i = threadIdx.x; i < 32 * (DIN / 4); i += 256) {
        int r = i >> 5, c4 = i & 31;
        ((float4*)xs[r])[c4] = ((const float4*)(x + (size_t)(row0 + r) * DIN))[c4];
    }

    const int j = threadIdx.x & 127;   // output column
    const int g = threadIdx.x >> 7;    // row group (0/1), 16 rows each
    float acc[16];
#pragma unroll
    for (int r = 0; r < 16; ++r) acc[r] = 0.f;

    for (int kk = 0; kk < 2; ++kk) {
        __syncthreads();
        for (int i = threadIdx.x; i < 64 * (DH / 4); i += 256)
            ((float4*)Wl)[i] = ((const float4*)(W + (size_t)kk * 64 * DH))[i];
        __syncthreads();
#pragma unroll 4
        for (int k = 0; k < 64; ++k) {
            float w = Wl[k * DH + j];            // stride-1 across lanes: 2-way alias, free
#pragma unroll
            for (int r = 0; r < 16; ++r)
                acc[r] += xs[g * 16 + r][kk * 64 + k] * w;   // LDS broadcast
        }
    }
#pragma unroll
    for (int r = 0; r < 16; ++r) {
        int gr = row0 + g * 16 + r;
        float v = acc[r] * dinv[gr];
        h[(size_t)gr * DH + j] = v;
        agg[(size_t)gr * DH + j] = v;    // init agg with self-loop term
    }
}

// ---------------- layer-1 scatter: agg1[dst] += h1[src], 128 feats/edge ------
__global__ __launch_bounds__(256) void k_scatter1(
    const int* __restrict__ src, const int* __restrict__ dst,
    const float* __restrict__ h, float* __restrict__ agg, int E)
{
    int e = blockIdx.x * 2 + (threadIdx.x >> 7);
    int j = threadIdx.x & 127;
    if (e < E) {
        int s = src[e], d = dst[e];
        atomicAdd(&agg[(size_t)d * DH + j], h[(size_t)s * DH + j]);
    }
}

// ---------------- layer-2 GEMM (fused epilogue of layer 1) -------------------
// xs = relu(dinv*agg1 + b1);  h2 = dinv * (xs @ W2);  agg2 = h2
__global__ __launch_bounds__(256) void k_gemm2(
    const float* __restrict__ agg1, const float* __restrict__ W,
    const float* __restrict__ b1, const float* __restrict__ dinv,
    float* __restrict__ h, float* __restrict__ agg)
{
    __shared__ float Wl[DH * DOUT];  // 32KB full W2
    __shared__ float xs[32][DH];     // 16KB
    const int row0 = blockIdx.x * 32;

    for (int i = threadIdx.x; i < (DH * DOUT) / 4; i += 256)
        ((float4*)Wl)[i] = ((const float4*)W)[i];
    for (int i = threadIdx.x; i < 32 * DH; i += 256) {
        int r = i >> 7, c = i & 127;
        int gr = row0 + r;
        float v = dinv[gr] * agg1[(size_t)gr * DH + c] + b1[c];
        xs[r][c] = v > 0.f ? v : 0.f;
    }
    __syncthreads();

    const int j = threadIdx.x & 63;    // output column
    const int g = threadIdx.x >> 6;    // row group (0..3), 8 rows each
    float acc[8];
#pragma unroll
    for (int r = 0; r < 8; ++r) acc[r] = 0.f;
#pragma unroll 4
    for (int k = 0; k < DH; ++k) {
        float w = Wl[k * DOUT + j];
#pragma unroll
        for (int r = 0; r < 8; ++r)
            acc[r] += xs[g * 8 + r][k] * w;
    }
#pragma unroll
    for (int r = 0; r < 8; ++r) {
        int gr = row0 + g * 8 + r;
        float v = acc[r] * dinv[gr];
        h[(size_t)gr * DOUT + j] = v;
        agg[(size_t)gr * DOUT + j] = v;
    }
}

// ---------------- layer-2 scatter: 64 feats/edge -----------------------------
__global__ __launch_bounds__(256) void k_scatter2(
    const int* __restrict__ src, const int* __restrict__ dst,
    const float* __restrict__ h, float* __restrict__ agg, int E)
{
    int e = blockIdx.x * 4 + (threadIdx.x >> 6);
    int j = threadIdx.x & 63;
    if (e < E) {
        int s = src[e], d = dst[e];
        atomicAdd(&agg[(size_t)d * DOUT + j], h[(size_t)s * DOUT + j]);
    }
}

// ---------------- final: out = dinv*agg2 + b2 --------------------------------
__global__ void k_final(const float* __restrict__ agg2, const float* __restrict__ dinv,
                        const float* __restrict__ b2, float* __restrict__ out, int n)
{
    int i = blockIdx.x * 256 + threadIdx.x;
    if (i < n * DOUT) {
        int node = i >> 6, c = i & 63;
        out[i] = dinv[node] * agg2[i] + b2[c];
    }
}

extern "C" void kernel_launch(void* const* d_in, const int* in_sizes, int n_in,
                              void* d_out, int out_size, void* d_ws, size_t ws_size,
                              hipStream_t stream) {
    const float* x  = (const float*)d_in[0];
    const int*   ei = (const int*)d_in[1];   // [2, E] int32 (jax x64-off downcast)
    const float* W1 = (const float*)d_in[2];
    const float* b1 = (const float*)d_in[3];
    const float* W2 = (const float*)d_in[4];
    const float* b2 = (const float*)d_in[5];
    float* out = (float*)d_out;

    const int n = N_NODES, E = NEDGES;
    const int* src = ei;
    const int* dst = ei + E;

    // Workspace layout (bytes), ~41.3 MB total with reuse:
    //   [0, 160000)            deg (int)
    //   [163840, 323840)       dinv (float)
    //   [327680, +20.48MB)     h1  -- dead after scatter1; reused: h2 then agg2
    //   [20807680, +20.48MB)   agg1
    char* ws = (char*)d_ws;
    int*   deg  = (int*)(ws + 0);
    float* dinv = (float*)(ws + 163840);
    float* h1   = (float*)(ws + 327680);
    float* agg1 = (float*)(ws + 20807680);
    float* h2   = h1;                                  // 10.24MB
    float* agg2 = (float*)(ws + 327680 + 10240000);    // 10.24MB, ends at agg1

    k_deg_init <<<(n + 255) / 256, 256, 0, stream>>>(deg, n);
    k_deg_accum<<<(E + 255) / 256, 256, 0, stream>>>(dst, deg, E);
    k_dinv     <<<(n + 255) / 256, 256, 0, stream>>>(deg, dinv, n);

    k_gemm1    <<<n / 32,  256, 0, stream>>>(x, W1, dinv, h1, agg1);
    k_scatter1 <<<E / 2,   256, 0, stream>>>(src, dst, h1, agg1, E);

    k_gemm2    <<<n / 32,  256, 0, stream>>>(agg1, W2, b1, dinv, h2, agg2);
    k_scatter2 <<<E / 4,   256, 0, stream>>>(src, dst, h2, agg2, E);

    k_final    <<<(n * DOUT + 255) / 256, 256, 0, stream>>>(agg2, dinv, b2, out, n);
}

// Round 2
// 334.925 us; speedup vs baseline: 1.7399x; 1.7399x over previous
//
#include <hip/hip_runtime.h>

// ClassicalGCN: 2-layer GCN, N=40000, E=640000, 128 -> 128(relu) -> 64, f32.
// Round 2: replace atomic scatter (272us, atomic-throughput-bound) with
// CSR counting-sort + per-node gather-reduce (no float atomics).
// Pipeline: deg -> scan(offsets,dinv,cursor) -> bucket -> gemm1 ->
//           agg1(fused relu/bias epilogue) -> gemm2 -> agg2(writes d_out).

#define N_NODES 40000
#define DIN 128
#define DH 128
#define DOUT 64
#define NEDGES 640000

// ---------------- CSR build ----------------
__global__ void k_deg_init(int* __restrict__ deg, int n) {
    int i = blockIdx.x * 256 + threadIdx.x;
    if (i < n) deg[i] = 0;
}

__global__ void k_deg_accum(const int* __restrict__ dst, int* __restrict__ deg, int E) {
    int e = blockIdx.x * 256 + threadIdx.x;
    if (e < E) atomicAdd(&deg[dst[e]], 1);
}

// Single-block scan over N: offsets (exclusive, [n+1]), cursor (= exclusive),
// dinv = rsqrt(deg+1)  (+1 self-loop).
__global__ __launch_bounds__(1024) void k_scan(
    const int* __restrict__ deg, int* __restrict__ offsets,
    int* __restrict__ cursor, float* __restrict__ dinv, int n)
{
    __shared__ int buf[1024];
    __shared__ int carry_s;
    if (threadIdx.x == 0) { carry_s = 0; offsets[0] = 0; }
    __syncthreads();
    for (int base = 0; base < n; base += 1024) {
        int i = base + threadIdx.x;
        int v = (i < n) ? deg[i] : 0;
        buf[threadIdx.x] = v;
        __syncthreads();
        for (int off = 1; off < 1024; off <<= 1) {
            int t = (threadIdx.x >= off) ? buf[threadIdx.x - off] : 0;
            __syncthreads();
            buf[threadIdx.x] += t;
            __syncthreads();
        }
        int incl = buf[threadIdx.x] + carry_s;
        if (i < n) {
            offsets[i + 1] = incl;
            cursor[i] = incl - v;                 // exclusive prefix
            dinv[i] = rsqrtf((float)(v + 1));     // self-loop included
        }
        __syncthreads();
        if (threadIdx.x == 1023) carry_s = incl;
        __syncthreads();
    }
}

// Sort edge srcs into dst-buckets.
__global__ void k_bucket(const int* __restrict__ src, const int* __restrict__ dst,
                         int* __restrict__ cursor, int* __restrict__ ssrc, int E) {
    int e = blockIdx.x * 256 + threadIdx.x;
    if (e < E) {
        int d = dst[e];
        int p = atomicAdd(&cursor[d], 1);
        ssrc[p] = src[e];
    }
}

// ---------------- layer-1 GEMM:  h1 = dinv * (x @ W1) ----------------
__global__ __launch_bounds__(256) void k_gemm1(
    const float* __restrict__ x, const float* __restrict__ W,
    const float* __restrict__ dinv, float* __restrict__ h)
{
    __shared__ float Wl[64 * DH];    // 32KB half of W1
    __shared__ float xs[32][DIN];    // 16KB
    const int row0 = blockIdx.x * 32;

    for (int i = threadIdx.x; i < 32 * (DIN / 4); i += 256) {
        int r = i >> 5, c4 = i & 31;
        ((float4*)xs[r])[c4] = ((const float4*)(x + (size_t)(row0 + r) * DIN))[c4];
    }

    const int j = threadIdx.x & 127;   // output column
    const int g = threadIdx.x >> 7;    // row group (0/1), 16 rows each
    float acc[16];
#pragma unroll
    for (int r = 0; r < 16; ++r) acc[r] = 0.f;

    for (int kk = 0; kk < 2; ++kk) {
        __syncthreads();
        for (int i = threadIdx.x; i < 64 * (DH / 4); i += 256)
            ((float4*)Wl)[i] = ((const float4*)(W + (size_t)kk * 64 * DH))[i];
        __syncthreads();
#pragma unroll 4
        for (int k = 0; k < 64; ++k) {
            float w = Wl[k * DH + j];
#pragma unroll
            for (int r = 0; r < 16; ++r)
                acc[r] += xs[g * 16 + r][kk * 64 + k] * w;
        }
    }
#pragma unroll
    for (int r = 0; r < 16; ++r) {
        int gr = row0 + g * 16 + r;
        h[(size_t)gr * DH + j] = acc[r] * dinv[gr];
    }
}

// ---------------- layer-1 gather-reduce + fused epilogue ----------------
// One wave per node; lane covers 2 features (float2). x2 = relu(dinv*sum + b1).
__global__ __launch_bounds__(256) void k_agg1(
    const int* __restrict__ offsets, const int* __restrict__ ssrc,
    const float* __restrict__ h, const float* __restrict__ dinv,
    const float* __restrict__ b1, float* __restrict__ x2)
{
    const int node = blockIdx.x * 4 + (threadIdx.x >> 6);
    const int lane = threadIdx.x & 63;
    const float2* hp = (const float2*)h;
    float2 acc = hp[(size_t)node * 64 + lane];    // self-loop term
    const int begin = offsets[node], end = offsets[node + 1];
    for (int base = begin; base < end; base += 64) {
        const int cnt = min(64, end - base);
        int sv = (base + lane < end) ? ssrc[base + lane] : 0;
        int e = 0;
        for (; e + 4 <= cnt; e += 4) {
            int s0 = __shfl(sv, e), s1 = __shfl(sv, e + 1);
            int s2 = __shfl(sv, e + 2), s3 = __shfl(sv, e + 3);
            float2 v0 = hp[(size_t)s0 * 64 + lane];
            float2 v1 = hp[(size_t)s1 * 64 + lane];
            float2 v2 = hp[(size_t)s2 * 64 + lane];
            float2 v3 = hp[(size_t)s3 * 64 + lane];
            acc.x += (v0.x + v1.x) + (v2.x + v3.x);
            acc.y += (v0.y + v1.y) + (v2.y + v3.y);
        }
        for (; e < cnt; ++e) {
            int s = __shfl(sv, e);
            float2 v = hp[(size_t)s * 64 + lane];
            acc.x += v.x; acc.y += v.y;
        }
    }
    const float dn = dinv[node];
    float vx = dn * acc.x + b1[2 * lane];
    float vy = dn * acc.y + b1[2 * lane + 1];
    float2 o;
    o.x = vx > 0.f ? vx : 0.f;
    o.y = vy > 0.f ? vy : 0.f;
    ((float2*)x2)[(size_t)node * 64 + lane] = o;
}

// ---------------- layer-2 GEMM:  h2 = dinv * (x2 @ W2) ----------------
__global__ __launch_bounds__(256) void k_gemm2(
    const float* __restrict__ x2, const float* __restrict__ W,
    const float* __restrict__ dinv, float* __restrict__ h)
{
    __shared__ float Wl[DH * DOUT];  // 32KB full W2
    __shared__ float xs[32][DH];     // 16KB
    const int row0 = blockIdx.x * 32;

    for (int i = threadIdx.x; i < (DH * DOUT) / 4; i += 256)
        ((float4*)Wl)[i] = ((const float4*)W)[i];
    for (int i = threadIdx.x; i < 32 * (DH / 4); i += 256) {
        int r = i >> 5, c4 = i & 31;
        ((float4*)xs[r])[c4] = ((const float4*)(x2 + (size_t)(row0 + r) * DH))[c4];
    }
    __syncthreads();

    const int j = threadIdx.x & 63;    // output column
    const int g = threadIdx.x >> 6;    // row group (0..3), 8 rows each
    float acc[8];
#pragma unroll
    for (int r = 0; r < 8; ++r) acc[r] = 0.f;
#pragma unroll 4
    for (int k = 0; k < DH; ++k) {
        float w = Wl[k * DOUT + j];
#pragma unroll
        for (int r = 0; r < 8; ++r)
            acc[r] += xs[g * 8 + r][k] * w;
    }
#pragma unroll
    for (int r = 0; r < 8; ++r) {
        int gr = row0 + g * 8 + r;
        h[(size_t)gr * DOUT + j] = acc[r] * dinv[gr];
    }
}

// ---------------- layer-2 gather-reduce, writes final output ----------------
// One wave per node; lane = feature. out = dinv*sum + b2.
__global__ __launch_bounds__(256) void k_agg2(
    const int* __restrict__ offsets, const int* __restrict__ ssrc,
    const float* __restrict__ h, const float* __restrict__ dinv,
    const float* __restrict__ b2, float* __restrict__ out)
{
    const int node = blockIdx.x * 4 + (threadIdx.x >> 6);
    const int lane = threadIdx.x & 63;
    float acc = h[(size_t)node * 64 + lane];      // self-loop term
    const int begin = offsets[node], end = offsets[node + 1];
    for (int base = begin; base < end; base += 64) {
        const int cnt = min(64, end - base);
        int sv = (base + lane < end) ? ssrc[base + lane] : 0;
        int e = 0;
        for (; e + 4 <= cnt; e += 4) {
            int s0 = __shfl(sv, e), s1 = __shfl(sv, e + 1);
            int s2 = __shfl(sv, e + 2), s3 = __shfl(sv, e + 3);
            float v0 = h[(size_t)s0 * 64 + lane];
            float v1 = h[(size_t)s1 * 64 + lane];
            float v2 = h[(size_t)s2 * 64 + lane];
            float v3 = h[(size_t)s3 * 64 + lane];
            acc += (v0 + v1) + (v2 + v3);
        }
        for (; e < cnt; ++e) {
            int s = __shfl(sv, e);
            acc += h[(size_t)s * 64 + lane];
        }
    }
    out[(size_t)node * 64 + lane] = dinv[node] * acc + b2[lane];
}

extern "C" void kernel_launch(void* const* d_in, const int* in_sizes, int n_in,
                              void* d_out, int out_size, void* d_ws, size_t ws_size,
                              hipStream_t stream) {
    const float* x  = (const float*)d_in[0];
    const int*   ei = (const int*)d_in[1];   // [2, E] int32
    const float* W1 = (const float*)d_in[2];
    const float* b1 = (const float*)d_in[3];
    const float* W2 = (const float*)d_in[4];
    const float* b2 = (const float*)d_in[5];
    float* out = (float*)d_out;

    const int n = N_NODES, E = NEDGES;
    const int* src = ei;
    const int* dst = ei + E;

    // Workspace layout (bytes), ~44.2 MB:
    char* ws = (char*)d_ws;
    int*   deg     = (int*)(ws + 0);          // 160000
    int*   offsets = (int*)(ws + 163840);     // 160004
    int*   cursor  = (int*)(ws + 327680);     // 160000
    float* dinv    = (float*)(ws + 491520);   // 160000
    int*   ssrc    = (int*)(ws + 655360);     // 2560000
    float* h1      = (float*)(ws + 3215360);  // 20.48MB ; reused as h2 (10.24MB)
    float* x2      = (float*)(ws + 23695360); // 20.48MB
    float* h2      = h1;

    k_deg_init <<<(n + 255) / 256, 256, 0, stream>>>(deg, n);
    k_deg_accum<<<(E + 255) / 256, 256, 0, stream>>>(dst, deg, E);
    k_scan     <<<1, 1024, 0, stream>>>(deg, offsets, cursor, dinv, n);
    k_bucket   <<<(E + 255) / 256, 256, 0, stream>>>(src, dst, cursor, ssrc, E);

    k_gemm1    <<<n / 32, 256, 0, stream>>>(x, W1, dinv, h1);
    k_agg1     <<<n / 4,  256, 0, stream>>>(offsets, ssrc, h1, dinv, b1, x2);

    k_gemm2    <<<n / 32, 256, 0, stream>>>(x2, W2, dinv, h2);
    k_agg2     <<<n / 4,  256, 0, stream>>>(offsets, ssrc, h2, dinv, b2, out);
}

// Round 3
// 266.793 us; speedup vs baseline: 2.1843x; 1.2554x over previous
//
#include <hip/hip_runtime.h>

// ClassicalGCN: 2-layer GCN, N=40000, E=640000, 128 -> 128(relu) -> 64, f32.
// Round 3: replace single-block serial scan (77us, 0.17% occupancy) with
// hierarchical 3-kernel scan (local shfl-scan -> block-sum scan -> apply).
// Pipeline: deg -> scan3 -> bucket -> gemm1 -> agg1(fused relu/bias) ->
//           gemm2 -> agg2(writes d_out).

#define N_NODES 40000
#define DIN 128
#define DH 128
#define DOUT 64
#define NEDGES 640000
#define SCAN_BLOCKS 40   // ceil(N / 1024)

// ---------------- CSR build ----------------
__global__ void k_deg_init(int* __restrict__ deg, int n) {
    int i = blockIdx.x * 256 + threadIdx.x;
    if (i < n) deg[i] = 0;
}

__global__ void k_deg_accum(const int* __restrict__ dst, int* __restrict__ deg, int E) {
    int e = blockIdx.x * 256 + threadIdx.x;
    if (e < E) atomicAdd(&deg[dst[e]], 1);
}

// Per-block inclusive scan (1024 elems/block): wave shfl-scan + wave-sum combine.
__global__ __launch_bounds__(1024) void k_scan_local(
    const int* __restrict__ deg, int* __restrict__ offsets,
    int* __restrict__ bsum, int n)
{
    const int i = blockIdx.x * 1024 + threadIdx.x;
    const int lane = threadIdx.x & 63, wid = threadIdx.x >> 6;
    int v = (i < n) ? deg[i] : 0;
    int s = v;
#pragma unroll
    for (int off = 1; off < 64; off <<= 1) {
        int t = __shfl_up(s, off);
        if (lane >= off) s += t;
    }
    __shared__ int wsum[16];
    if (lane == 63) wsum[wid] = s;
    __syncthreads();
    if (threadIdx.x < 16) {
        int ws = wsum[threadIdx.x];
#pragma unroll
        for (int off = 1; off < 16; off <<= 1) {
            int t = __shfl_up(ws, off);
            if (threadIdx.x >= off) ws += t;
        }
        wsum[threadIdx.x] = ws;
    }
    __syncthreads();
    int incl = s + (wid > 0 ? wsum[wid - 1] : 0);
    if (i < n) offsets[i + 1] = incl;                 // pre-base local inclusive
    if (threadIdx.x == 1023) bsum[blockIdx.x] = incl; // block total (padding=0 safe)
}

// One wave: exclusive scan of SCAN_BLOCKS block totals, in place.
__global__ void k_scan_bsum(int* __restrict__ bsum) {
    int lane = threadIdx.x;
    int v = (lane < SCAN_BLOCKS) ? bsum[lane] : 0;
    int s = v;
#pragma unroll
    for (int off = 1; off < 64; off <<= 1) {
        int t = __shfl_up(s, off);
        if (lane >= off) s += t;
    }
    if (lane < SCAN_BLOCKS) bsum[lane] = s - v;       // exclusive base
}

// Add block base; emit offsets / cursor / dinv.
__global__ __launch_bounds__(1024) void k_scan_apply(
    const int* __restrict__ deg, int* __restrict__ offsets,
    const int* __restrict__ bsum, int* __restrict__ cursor,
    float* __restrict__ dinv, int n)
{
    const int i = blockIdx.x * 1024 + threadIdx.x;
    if (i == 0) offsets[0] = 0;
    if (i < n) {
        int incl = offsets[i + 1] + bsum[blockIdx.x];
        offsets[i + 1] = incl;
        int d = deg[i];
        cursor[i] = incl - d;                          // exclusive prefix
        dinv[i] = rsqrtf((float)(d + 1));              // +1 self-loop
    }
}

// Sort edge srcs into dst-buckets.
__global__ void k_bucket(const int* __restrict__ src, const int* __restrict__ dst,
                         int* __restrict__ cursor, int* __restrict__ ssrc, int E) {
    int e = blockIdx.x * 256 + threadIdx.x;
    if (e < E) {
        int d = dst[e];
        int p = atomicAdd(&cursor[d], 1);
        ssrc[p] = src[e];
    }
}

// ---------------- layer-1 GEMM:  h1 = dinv * (x @ W1) ----------------
__global__ __launch_bounds__(256) void k_gemm1(
    const float* __restrict__ x, const float* __restrict__ W,
    const float* __restrict__ dinv, float* __restrict__ h)
{
    __shared__ float Wl[64 * DH];    // 32KB half of W1
    __shared__ float xs[32][DIN];    // 16KB
    const int row0 = blockIdx.x * 32;

    for (int i = threadIdx.x; i < 32 * (DIN / 4); i += 256) {
        int r = i >> 5, c4 = i & 31;
        ((float4*)xs[r])[c4] = ((const float4*)(x + (size_t)(row0 + r) * DIN))[c4];
    }

    const int j = threadIdx.x & 127;   // output column
    const int g = threadIdx.x >> 7;    // row group (0/1), 16 rows each
    float acc[16];
#pragma unroll
    for (int r = 0; r < 16; ++r) acc[r] = 0.f;

    for (int kk = 0; kk < 2; ++kk) {
        __syncthreads();
        for (int i = threadIdx.x; i < 64 * (DH / 4); i += 256)
            ((float4*)Wl)[i] = ((const float4*)(W + (size_t)kk * 64 * DH))[i];
        __syncthreads();
#pragma unroll 4
        for (int k = 0; k < 64; ++k) {
            float w = Wl[k * DH + j];
#pragma unroll
            for (int r = 0; r < 16; ++r)
                acc[r] += xs[g * 16 + r][kk * 64 + k] * w;
        }
    }
#pragma unroll
    for (int r = 0; r < 16; ++r) {
        int gr = row0 + g * 16 + r;
        h[(size_t)gr * DH + j] = acc[r] * dinv[gr];
    }
}

// ---------------- layer-1 gather-reduce + fused epilogue ----------------
__global__ __launch_bounds__(256) void k_agg1(
    const int* __restrict__ offsets, const int* __restrict__ ssrc,
    const float* __restrict__ h, const float* __restrict__ dinv,
    const float* __restrict__ b1, float* __restrict__ x2)
{
    const int node = blockIdx.x * 4 + (threadIdx.x >> 6);
    const int lane = threadIdx.x & 63;
    const float2* hp = (const float2*)h;
    float2 acc = hp[(size_t)node * 64 + lane];    // self-loop term
    const int begin = offsets[node], end = offsets[node + 1];
    for (int base = begin; base < end; base += 64) {
        const int cnt = min(64, end - base);
        int sv = (base + lane < end) ? ssrc[base + lane] : 0;
        int e = 0;
        for (; e + 4 <= cnt; e += 4) {
            int s0 = __shfl(sv, e), s1 = __shfl(sv, e + 1);
            int s2 = __shfl(sv, e + 2), s3 = __shfl(sv, e + 3);
            float2 v0 = hp[(size_t)s0 * 64 + lane];
            float2 v1 = hp[(size_t)s1 * 64 + lane];
            float2 v2 = hp[(size_t)s2 * 64 + lane];
            float2 v3 = hp[(size_t)s3 * 64 + lane];
            acc.x += (v0.x + v1.x) + (v2.x + v3.x);
            acc.y += (v0.y + v1.y) + (v2.y + v3.y);
        }
        for (; e < cnt; ++e) {
            int s = __shfl(sv, e);
            float2 v = hp[(size_t)s * 64 + lane];
            acc.x += v.x; acc.y += v.y;
        }
    }
    const float dn = dinv[node];
    float vx = dn * acc.x + b1[2 * lane];
    float vy = dn * acc.y + b1[2 * lane + 1];
    float2 o;
    o.x = vx > 0.f ? vx : 0.f;
    o.y = vy > 0.f ? vy : 0.f;
    ((float2*)x2)[(size_t)node * 64 + lane] = o;
}

// ---------------- layer-2 GEMM:  h2 = dinv * (x2 @ W2) ----------------
__global__ __launch_bounds__(256) void k_gemm2(
    const float* __restrict__ x2, const float* __restrict__ W,
    const float* __restrict__ dinv, float* __restrict__ h)
{
    __shared__ float Wl[DH * DOUT];  // 32KB full W2
    __shared__ float xs[32][DH];     // 16KB
    const int row0 = blockIdx.x * 32;

    for (int i = threadIdx.x; i < (DH * DOUT) / 4; i += 256)
        ((float4*)Wl)[i] = ((const float4*)W)[i];
    for (int i = threadIdx.x; i < 32 * (DH / 4); i += 256) {
        int r = i >> 5, c4 = i & 31;
        ((float4*)xs[r])[c4] = ((const float4*)(x2 + (size_t)(row0 + r) * DH))[c4];
    }
    __syncthreads();

    const int j = threadIdx.x & 63;    // output column
    const int g = threadIdx.x >> 6;    // row group (0..3), 8 rows each
    float acc[8];
#pragma unroll
    for (int r = 0; r < 8; ++r) acc[r] = 0.f;
#pragma unroll 4
    for (int k = 0; k < DH; ++k) {
        float w = Wl[k * DOUT + j];
#pragma unroll
        for (int r = 0; r < 8; ++r)
            acc[r] += xs[g * 8 + r][k] * w;
    }
#pragma unroll
    for (int r = 0; r < 8; ++r) {
        int gr = row0 + g * 8 + r;
        h[(size_t)gr * DOUT + j] = acc[r] * dinv[gr];
    }
}

// ---------------- layer-2 gather-reduce, writes final output ----------------
__global__ __launch_bounds__(256) void k_agg2(
    const int* __restrict__ offsets, const int* __restrict__ ssrc,
    const float* __restrict__ h, const float* __restrict__ dinv,
    const float* __restrict__ b2, float* __restrict__ out)
{
    const int node = blockIdx.x * 4 + (threadIdx.x >> 6);
    const int lane = threadIdx.x & 63;
    float acc = h[(size_t)node * 64 + lane];      // self-loop term
    const int begin = offsets[node], end = offsets[node + 1];
    for (int base = begin; base < end; base += 64) {
        const int cnt = min(64, end - base);
        int sv = (base + lane < end) ? ssrc[base + lane] : 0;
        int e = 0;
        for (; e + 4 <= cnt; e += 4) {
            int s0 = __shfl(sv, e), s1 = __shfl(sv, e + 1);
            int s2 = __shfl(sv, e + 2), s3 = __shfl(sv, e + 3);
            float v0 = h[(size_t)s0 * 64 + lane];
            float v1 = h[(size_t)s1 * 64 + lane];
            float v2 = h[(size_t)s2 * 64 + lane];
            float v3 = h[(size_t)s3 * 64 + lane];
            acc += (v0 + v1) + (v2 + v3);
        }
        for (; e < cnt; ++e) {
            int s = __shfl(sv, e);
            acc += h[(size_t)s * 64 + lane];
        }
    }
    out[(size_t)node * 64 + lane] = dinv[node] * acc + b2[lane];
}

extern "C" void kernel_launch(void* const* d_in, const int* in_sizes, int n_in,
                              void* d_out, int out_size, void* d_ws, size_t ws_size,
                              hipStream_t stream) {
    const float* x  = (const float*)d_in[0];
    const int*   ei = (const int*)d_in[1];   // [2, E] int32
    const float* W1 = (const float*)d_in[2];
    const float* b1 = (const float*)d_in[3];
    const float* W2 = (const float*)d_in[4];
    const float* b2 = (const float*)d_in[5];
    float* out = (float*)d_out;

    const int n = N_NODES, E = NEDGES;
    const int* src = ei;
    const int* dst = ei + E;

    // Workspace layout (bytes), ~44.2 MB (bsum lives in deg's padding):
    char* ws = (char*)d_ws;
    int*   deg     = (int*)(ws + 0);          // 160000
    int*   bsum    = (int*)(ws + 160000);     // 160   (padding of deg slot)
    int*   offsets = (int*)(ws + 163840);     // 160004
    int*   cursor  = (int*)(ws + 327680);     // 160000
    float* dinv    = (float*)(ws + 491520);   // 160000
    int*   ssrc    = (int*)(ws + 655360);     // 2560000
    float* h1      = (float*)(ws + 3215360);  // 20.48MB ; reused as h2 (10.24MB)
    float* x2      = (float*)(ws + 23695360); // 20.48MB
    float* h2      = h1;

    k_deg_init  <<<(n + 255) / 256, 256, 0, stream>>>(deg, n);
    k_deg_accum <<<(E + 255) / 256, 256, 0, stream>>>(dst, deg, E);
    k_scan_local<<<SCAN_BLOCKS, 1024, 0, stream>>>(deg, offsets, bsum, n);
    k_scan_bsum <<<1, 64, 0, stream>>>(bsum);
    k_scan_apply<<<SCAN_BLOCKS, 1024, 0, stream>>>(deg, offsets, bsum, cursor, dinv, n);
    k_bucket    <<<(E + 255) / 256, 256, 0, stream>>>(src, dst, cursor, ssrc, E);

    k_gemm1     <<<n / 32, 256, 0, stream>>>(x, W1, dinv, h1);
    k_agg1      <<<n / 4,  256, 0, stream>>>(offsets, ssrc, h1, dinv, b1, x2);

    k_gemm2     <<<n / 32, 256, 0, stream>>>(x2, W2, dinv, h2);
    k_agg2      <<<n / 4,  256, 0, stream>>>(offsets, ssrc, h2, dinv, b2, out);
}

// Round 5
// 257.428 us; speedup vs baseline: 2.2637x; 1.0364x over previous
//
#include <hip/hip_runtime.h>
#include <hip/hip_fp16.h>

// ClassicalGCN: 2-layer GCN, N=40000, E=640000, 128 -> 128(relu) -> 64, f32.
// Round 5:
//  - REVERT agg kernels to round-3 proven structure (round-4's cross-half
//    pairing diverged post-timing; also gave no speedup -> gather is
//    LLC-BW-bound, not issue-bound).
//  - h1 gather table in fp16 (rel err 2^-11): halves gather bytes, table
//    10.2 MB -> better per-XCD L2 hit rate. h2/agg2 stay fp32.
//  - keep round-4 all-b128 GEMM rebuilds (deterministic).

#define N_NODES 40000
#define DIN 128
#define DH 128
#define DOUT 64
#define NEDGES 640000
#define SCAN_BLOCKS 40   // ceil(N / 1024)

// ---------------- CSR build ----------------
__global__ void k_deg_init(int* __restrict__ deg, int n) {
    int i = blockIdx.x * 256 + threadIdx.x;
    if (i < n) deg[i] = 0;
}

__global__ void k_deg_accum(const int* __restrict__ dst, int* __restrict__ deg, int E) {
    int e = blockIdx.x * 256 + threadIdx.x;
    if (e < E) atomicAdd(&deg[dst[e]], 1);
}

// Per-block inclusive scan (1024 elems/block): wave shfl-scan + wave-sum combine.
__global__ __launch_bounds__(1024) void k_scan_local(
    const int* __restrict__ deg, int* __restrict__ offsets,
    int* __restrict__ bsum, int n)
{
    const int i = blockIdx.x * 1024 + threadIdx.x;
    const int lane = threadIdx.x & 63, wid = threadIdx.x >> 6;
    int v = (i < n) ? deg[i] : 0;
    int s = v;
#pragma unroll
    for (int off = 1; off < 64; off <<= 1) {
        int t = __shfl_up(s, off);
        if (lane >= off) s += t;
    }
    __shared__ int wsum[16];
    if (lane == 63) wsum[wid] = s;
    __syncthreads();
    if (threadIdx.x < 16) {
        int ws = wsum[threadIdx.x];
#pragma unroll
        for (int off = 1; off < 16; off <<= 1) {
            int t = __shfl_up(ws, off);
            if (threadIdx.x >= off) ws += t;
        }
        wsum[threadIdx.x] = ws;
    }
    __syncthreads();
    int incl = s + (wid > 0 ? wsum[wid - 1] : 0);
    if (i < n) offsets[i + 1] = incl;
    if (threadIdx.x == 1023) bsum[blockIdx.x] = incl;
}

// One wave: exclusive scan of SCAN_BLOCKS block totals, in place.
__global__ void k_scan_bsum(int* __restrict__ bsum) {
    int lane = threadIdx.x;
    int v = (lane < SCAN_BLOCKS) ? bsum[lane] : 0;
    int s = v;
#pragma unroll
    for (int off = 1; off < 64; off <<= 1) {
        int t = __shfl_up(s, off);
        if (lane >= off) s += t;
    }
    if (lane < SCAN_BLOCKS) bsum[lane] = s - v;
}

// Add block base; emit offsets / cursor / dinv.
__global__ __launch_bounds__(1024) void k_scan_apply(
    const int* __restrict__ deg, int* __restrict__ offsets,
    const int* __restrict__ bsum, int* __restrict__ cursor,
    float* __restrict__ dinv, int n)
{
    const int i = blockIdx.x * 1024 + threadIdx.x;
    if (i == 0) offsets[0] = 0;
    if (i < n) {
        int incl = offsets[i + 1] + bsum[blockIdx.x];
        offsets[i + 1] = incl;
        int d = deg[i];
        cursor[i] = incl - d;
        dinv[i] = rsqrtf((float)(d + 1));   // +1 self-loop
    }
}

// Sort edge srcs into dst-buckets.
__global__ void k_bucket(const int* __restrict__ src, const int* __restrict__ dst,
                         int* __restrict__ cursor, int* __restrict__ ssrc, int E) {
    int e = blockIdx.x * 256 + threadIdx.x;
    if (e < E) {
        int d = dst[e];
        int p = atomicAdd(&cursor[d], 1);
        ssrc[p] = src[e];
    }
}

// ---------------- layer-1 GEMM:  h1 = fp16( dinv * (x @ W1) ) ----------------
// 64 rows x 128 cols / block, 256 threads; thread = 8 rows x 4 cols, all-b128 LDS.
__global__ __launch_bounds__(256) void k_gemm1(
    const float* __restrict__ x, const float* __restrict__ W,
    const float* __restrict__ dinv, __half* __restrict__ h)
{
    __shared__ float xs[64][DIN];   // 32 KB
    __shared__ float Wl[64][DH];    // 32 KB (one 64-row half of W1 at a time)
    const int row0 = blockIdx.x * 64;
    const int j4 = threadIdx.x & 31;   // cols 4*j4 .. 4*j4+3
    const int g  = threadIdx.x >> 5;   // rows g*8 .. g*8+7

    for (int i = threadIdx.x; i < 64 * 32; i += 256) {
        int r = i >> 5, c4 = i & 31;
        ((float4*)xs[r])[c4] = ((const float4*)(x + (size_t)(row0 + r) * DIN))[c4];
    }

    float acc[8][4];
#pragma unroll
    for (int r = 0; r < 8; ++r)
#pragma unroll
        for (int c = 0; c < 4; ++c) acc[r][c] = 0.f;

    for (int kk = 0; kk < 2; ++kk) {
        __syncthreads();
        for (int i = threadIdx.x; i < 64 * 32; i += 256) {
            int r = i >> 5, c4 = i & 31;
            ((float4*)Wl[r])[c4] = ((const float4*)(W + (size_t)(kk * 64 + r) * DH))[c4];
        }
        __syncthreads();
#pragma unroll
        for (int k4 = 0; k4 < 16; ++k4) {
            float4 wv[4];
#pragma unroll
            for (int t = 0; t < 4; ++t)
                wv[t] = ((float4*)Wl[k4 * 4 + t])[j4];
#pragma unroll
            for (int r = 0; r < 8; ++r) {
                float4 xv = ((float4*)xs[g * 8 + r])[kk * 16 + k4];
                acc[r][0] += xv.x * wv[0].x + xv.y * wv[1].x + xv.z * wv[2].x + xv.w * wv[3].x;
                acc[r][1] += xv.x * wv[0].y + xv.y * wv[1].y + xv.z * wv[2].y + xv.w * wv[3].y;
                acc[r][2] += xv.x * wv[0].z + xv.y * wv[1].z + xv.z * wv[2].z + xv.w * wv[3].z;
                acc[r][3] += xv.x * wv[0].w + xv.y * wv[1].w + xv.z * wv[2].w + xv.w * wv[3].w;
            }
        }
    }
#pragma unroll
    for (int r = 0; r < 8; ++r) {
        int gr = row0 + g * 8 + r;
        float dn = dinv[gr];
        __half2 p0 = __floats2half2_rn(acc[r][0] * dn, acc[r][1] * dn);
        __half2 p1 = __floats2half2_rn(acc[r][2] * dn, acc[r][3] * dn);
        union { __half2 h2[2]; float2 f2; } u;
        u.h2[0] = p0; u.h2[1] = p1;
        ((float2*)(h + (size_t)gr * DH))[j4] = u.f2;   // 8B store = 4 fp16 feats
    }
}

// ---------------- layer-1 gather-reduce + fused epilogue ----------------
// Round-3 structure: one wave per node, lane = half2 feature pair (4B/lane,
// 256B/row-load), shfl-broadcast edge ids, 8 loads in flight, fp32 accum.
__global__ __launch_bounds__(256) void k_agg1(
    const int* __restrict__ offsets, const int* __restrict__ ssrc,
    const __half* __restrict__ h, const float* __restrict__ dinv,
    const float* __restrict__ b1, float* __restrict__ x2)
{
    const int node = blockIdx.x * 4 + (threadIdx.x >> 6);
    const int lane = threadIdx.x & 63;
    const __half2* hp = (const __half2*)h;   // 64 half2 per row
    float2 acc;
    {
        float2 s = __half22float2(hp[(size_t)node * 64 + lane]);  // self-loop term
        acc.x = s.x; acc.y = s.y;
    }
    const int begin = offsets[node], end = offsets[node + 1];
    for (int base = begin; base < end; base += 64) {
        const int cnt = min(64, end - base);
        int sv = (base + lane < end) ? ssrc[base + lane] : 0;
        int e = 0;
        for (; e + 8 <= cnt; e += 8) {
            int s0 = __shfl(sv, e),     s1 = __shfl(sv, e + 1);
            int s2 = __shfl(sv, e + 2), s3 = __shfl(sv, e + 3);
            int s4 = __shfl(sv, e + 4), s5 = __shfl(sv, e + 5);
            int s6 = __shfl(sv, e + 6), s7 = __shfl(sv, e + 7);
            float2 v0 = __half22float2(hp[(size_t)s0 * 64 + lane]);
            float2 v1 = __half22float2(hp[(size_t)s1 * 64 + lane]);
            float2 v2 = __half22float2(hp[(size_t)s2 * 64 + lane]);
            float2 v3 = __half22float2(hp[(size_t)s3 * 64 + lane]);
            float2 v4 = __half22float2(hp[(size_t)s4 * 64 + lane]);
            float2 v5 = __half22float2(hp[(size_t)s5 * 64 + lane]);
            float2 v6 = __half22float2(hp[(size_t)s6 * 64 + lane]);
            float2 v7 = __half22float2(hp[(size_t)s7 * 64 + lane]);
            acc.x += ((v0.x + v1.x) + (v2.x + v3.x)) + ((v4.x + v5.x) + (v6.x + v7.x));
            acc.y += ((v0.y + v1.y) + (v2.y + v3.y)) + ((v4.y + v5.y) + (v6.y + v7.y));
        }
        for (; e < cnt; ++e) {
            int s = __shfl(sv, e);
            float2 v = __half22float2(hp[(size_t)s * 64 + lane]);
            acc.x += v.x; acc.y += v.y;
        }
    }
    const float dn = dinv[node];
    float vx = dn * acc.x + b1[2 * lane];
    float vy = dn * acc.y + b1[2 * lane + 1];
    float2 o;
    o.x = vx > 0.f ? vx : 0.f;
    o.y = vy > 0.f ? vy : 0.f;
    ((float2*)x2)[(size_t)node * 64 + lane] = o;
}

// ---------------- layer-2 GEMM:  h2 = dinv * (x2 @ W2), fp32 ----------------
// 64 rows x 64 cols / block, 256 threads; thread = 4 rows x 4 cols, all-b128 LDS.
__global__ __launch_bounds__(256) void k_gemm2(
    const float* __restrict__ x2, const float* __restrict__ W,
    const float* __restrict__ dinv, float* __restrict__ h)
{
    __shared__ float xs[64][DH + 4];
    __shared__ float Wl[DH][DOUT];     // 32 KB full W2
    const int row0 = blockIdx.x * 64;
    const int j4 = threadIdx.x & 15;   // cols 4*j4 .. 4*j4+3
    const int g  = threadIdx.x >> 4;   // rows g*4 .. g*4+3

    for (int i = threadIdx.x; i < DH * 16; i += 256)
        ((float4*)Wl[i >> 4])[i & 15] = ((const float4*)W)[i];
    for (int i = threadIdx.x; i < 64 * 32; i += 256) {
        int r = i >> 5, c4 = i & 31;
        ((float4*)xs[r])[c4] = ((const float4*)(x2 + (size_t)(row0 + r) * DH))[c4];
    }
    __syncthreads();

    float acc[4][4];
#pragma unroll
    for (int r = 0; r < 4; ++r)
#pragma unroll
        for (int c = 0; c < 4; ++c) acc[r][c] = 0.f;

#pragma unroll
    for (int k4 = 0; k4 < 32; ++k4) {
        float4 wv[4];
#pragma unroll
        for (int t = 0; t < 4; ++t)
            wv[t] = ((float4*)Wl[k4 * 4 + t])[j4];
#pragma unroll
        for (int r = 0; r < 4; ++r) {
            float4 xv = ((float4*)xs[g * 4 + r])[k4];
            acc[r][0] += xv.x * wv[0].x + xv.y * wv[1].x + xv.z * wv[2].x + xv.w * wv[3].x;
            acc[r][1] += xv.x * wv[0].y + xv.y * wv[1].y + xv.z * wv[2].y + xv.w * wv[3].y;
            acc[r][2] += xv.x * wv[0].z + xv.y * wv[1].z + xv.z * wv[2].z + xv.w * wv[3].z;
            acc[r][3] += xv.x * wv[0].w + xv.y * wv[1].w + xv.z * wv[2].w + xv.w * wv[3].w;
        }
    }
#pragma unroll
    for (int r = 0; r < 4; ++r) {
        int gr = row0 + g * 4 + r;
        float dn = dinv[gr];
        float4 o = make_float4(acc[r][0] * dn, acc[r][1] * dn, acc[r][2] * dn, acc[r][3] * dn);
        ((float4*)(h + (size_t)gr * DOUT))[j4] = o;
    }
}

// ---------------- layer-2 gather-reduce, writes final output (round-3) ------
__global__ __launch_bounds__(256) void k_agg2(
    const int* __restrict__ offsets, const int* __restrict__ ssrc,
    const float* __restrict__ h, const float* __restrict__ dinv,
    const float* __restrict__ b2, float* __restrict__ out)
{
    const int node = blockIdx.x * 4 + (threadIdx.x >> 6);
    const int lane = threadIdx.x & 63;
    float acc = h[(size_t)node * 64 + lane];      // self-loop term
    const int begin = offsets[node], end = offsets[node + 1];
    for (int base = begin; base < end; base += 64) {
        const int cnt = min(64, end - base);
        int sv = (base + lane < end) ? ssrc[base + lane] : 0;
        int e = 0;
        for (; e + 4 <= cnt; e += 4) {
            int s0 = __shfl(sv, e), s1 = __shfl(sv, e + 1);
            int s2 = __shfl(sv, e + 2), s3 = __shfl(sv, e + 3);
            float v0 = h[(size_t)s0 * 64 + lane];
            float v1 = h[(size_t)s1 * 64 + lane];
            float v2 = h[(size_t)s2 * 64 + lane];
            float v3 = h[(size_t)s3 * 64 + lane];
            acc += (v0 + v1) + (v2 + v3);
        }
        for (; e < cnt; ++e) {
            int s = __shfl(sv, e);
            acc += h[(size_t)s * 64 + lane];
        }
    }
    out[(size_t)node * 64 + lane] = dinv[node] * acc + b2[lane];
}

extern "C" void kernel_launch(void* const* d_in, const int* in_sizes, int n_in,
                              void* d_out, int out_size, void* d_ws, size_t ws_size,
                              hipStream_t stream) {
    const float* x  = (const float*)d_in[0];
    const int*   ei = (const int*)d_in[1];   // [2, E] int32
    const float* W1 = (const float*)d_in[2];
    const float* b1 = (const float*)d_in[3];
    const float* W2 = (const float*)d_in[4];
    const float* b2 = (const float*)d_in[5];
    float* out = (float*)d_out;

    const int n = N_NODES, E = NEDGES;
    const int* src = ei;
    const int* dst = ei + E;

    // Workspace layout (bytes), ~44.2 MB:
    char* ws = (char*)d_ws;
    int*    deg     = (int*)(ws + 0);          // 160000
    int*    bsum    = (int*)(ws + 160000);     // 160 (padding of deg slot)
    int*    offsets = (int*)(ws + 163840);     // 160004
    int*    cursor  = (int*)(ws + 327680);     // 160000
    float*  dinv    = (float*)(ws + 491520);   // 160000
    int*    ssrc    = (int*)(ws + 655360);     // 2560000
    __half* h1      = (__half*)(ws + 3215360); // 10.24MB fp16 table
    float*  h2      = (float*)(ws + 13455360); // 10.24MB fp32
    float*  x2      = (float*)(ws + 23695360); // 20.48MB

    k_deg_init  <<<(n + 255) / 256, 256, 0, stream>>>(deg, n);
    k_deg_accum <<<(E + 255) / 256, 256, 0, stream>>>(dst, deg, E);
    k_scan_local<<<SCAN_BLOCKS, 1024, 0, stream>>>(deg, offsets, bsum, n);
    k_scan_bsum <<<1, 64, 0, stream>>>(bsum);
    k_scan_apply<<<SCAN_BLOCKS, 1024, 0, stream>>>(deg, offsets, bsum, cursor, dinv, n);
    k_bucket    <<<(E + 255) / 256, 256, 0, stream>>>(src, dst, cursor, ssrc, E);

    k_gemm1     <<<n / 64, 256, 0, stream>>>(x, W1, dinv, h1);
    k_agg1      <<<n / 4,  256, 0, stream>>>(offsets, ssrc, h1, dinv, b1, x2);

    k_gemm2     <<<n / 64, 256, 0, stream>>>(x2, W2, dinv, h2);
    k_agg2      <<<n / 4,  256, 0, stream>>>(offsets, ssrc, h2, dinv, b2, out);
}

// Round 6
// 234.624 us; speedup vs baseline: 2.4838x; 1.0972x over previous
//
#include <hip/hip_runtime.h>
#include <hip/hip_fp16.h>

// ClassicalGCN: 2-layer GCN, N=40000, E=640000, 128 -> 128(relu) -> 64, f32.
// Round 6: fix GEMM occupancy regression (r4 64-row tiles: 64KB LDS, 625
// blocks -> 8.4% occupancy, 50us). Now 32-row tiles, W staged in 16KB
// chunks -> 32KB LDS, 1250 blocks, 5 blocks/CU. Aggs unchanged (r5 proven).

#define N_NODES 40000
#define DIN 128
#define DH 128
#define DOUT 64
#define NEDGES 640000
#define SCAN_BLOCKS 40   // ceil(N / 1024)

// ---------------- CSR build ----------------
__global__ void k_deg_init(int* __restrict__ deg, int n) {
    int i = blockIdx.x * 256 + threadIdx.x;
    if (i < n) deg[i] = 0;
}

__global__ void k_deg_accum(const int* __restrict__ dst, int* __restrict__ deg, int E) {
    int e = blockIdx.x * 256 + threadIdx.x;
    if (e < E) atomicAdd(&deg[dst[e]], 1);
}

// Per-block inclusive scan (1024 elems/block): wave shfl-scan + wave-sum combine.
__global__ __launch_bounds__(1024) void k_scan_local(
    const int* __restrict__ deg, int* __restrict__ offsets,
    int* __restrict__ bsum, int n)
{
    const int i = blockIdx.x * 1024 + threadIdx.x;
    const int lane = threadIdx.x & 63, wid = threadIdx.x >> 6;
    int v = (i < n) ? deg[i] : 0;
    int s = v;
#pragma unroll
    for (int off = 1; off < 64; off <<= 1) {
        int t = __shfl_up(s, off);
        if (lane >= off) s += t;
    }
    __shared__ int wsum[16];
    if (lane == 63) wsum[wid] = s;
    __syncthreads();
    if (threadIdx.x < 16) {
        int ws = wsum[threadIdx.x];
#pragma unroll
        for (int off = 1; off < 16; off <<= 1) {
            int t = __shfl_up(ws, off);
            if (threadIdx.x >= off) ws += t;
        }
        wsum[threadIdx.x] = ws;
    }
    __syncthreads();
    int incl = s + (wid > 0 ? wsum[wid - 1] : 0);
    if (i < n) offsets[i + 1] = incl;
    if (threadIdx.x == 1023) bsum[blockIdx.x] = incl;
}

// One wave: exclusive scan of SCAN_BLOCKS block totals, in place.
__global__ void k_scan_bsum(int* __restrict__ bsum) {
    int lane = threadIdx.x;
    int v = (lane < SCAN_BLOCKS) ? bsum[lane] : 0;
    int s = v;
#pragma unroll
    for (int off = 1; off < 64; off <<= 1) {
        int t = __shfl_up(s, off);
        if (lane >= off) s += t;
    }
    if (lane < SCAN_BLOCKS) bsum[lane] = s - v;
}

// Add block base; emit offsets / cursor / dinv.
__global__ __launch_bounds__(1024) void k_scan_apply(
    const int* __restrict__ deg, int* __restrict__ offsets,
    const int* __restrict__ bsum, int* __restrict__ cursor,
    float* __restrict__ dinv, int n)
{
    const int i = blockIdx.x * 1024 + threadIdx.x;
    if (i == 0) offsets[0] = 0;
    if (i < n) {
        int incl = offsets[i + 1] + bsum[blockIdx.x];
        offsets[i + 1] = incl;
        int d = deg[i];
        cursor[i] = incl - d;
        dinv[i] = rsqrtf((float)(d + 1));   // +1 self-loop
    }
}

// Sort edge srcs into dst-buckets.
__global__ void k_bucket(const int* __restrict__ src, const int* __restrict__ dst,
                         int* __restrict__ cursor, int* __restrict__ ssrc, int E) {
    int e = blockIdx.x * 256 + threadIdx.x;
    if (e < E) {
        int d = dst[e];
        int p = atomicAdd(&cursor[d], 1);
        ssrc[p] = src[e];
    }
}

// ---------------- layer-1 GEMM:  h1 = fp16( dinv * (x @ W1) ) ----------------
// 32 rows x 128 cols / block, 256 threads; thread = 4 rows x 4 cols.
// LDS 32KB (xs 16KB + 16KB W-quarter x4 stages) -> 5 blocks/CU, 1250 blocks.
__global__ __launch_bounds__(256) void k_gemm1(
    const float* __restrict__ x, const float* __restrict__ W,
    const float* __restrict__ dinv, __half* __restrict__ h)
{
    __shared__ float xs[32][DIN];   // 16 KB
    __shared__ float Wl[32][DH];    // 16 KB (one 32-row quarter of W1)
    const int row0 = blockIdx.x * 32;
    const int j4 = threadIdx.x & 31;   // cols 4*j4 .. 4*j4+3
    const int g  = threadIdx.x >> 5;   // 0..7 -> rows g*4 .. g*4+3

    for (int i = threadIdx.x; i < 32 * 32; i += 256) {
        int r = i >> 5, c4 = i & 31;
        ((float4*)xs[r])[c4] = ((const float4*)(x + (size_t)(row0 + r) * DIN))[c4];
    }

    float acc[4][4];
#pragma unroll
    for (int r = 0; r < 4; ++r)
#pragma unroll
        for (int c = 0; c < 4; ++c) acc[r][c] = 0.f;

    for (int kk = 0; kk < 4; ++kk) {
        __syncthreads();   // kk=0: also covers xs staging
        for (int i = threadIdx.x; i < 32 * 32; i += 256) {
            int r = i >> 5, c4 = i & 31;
            ((float4*)Wl[r])[c4] = ((const float4*)(W + (size_t)(kk * 32 + r) * DH))[c4];
        }
        __syncthreads();
#pragma unroll
        for (int k4 = 0; k4 < 8; ++k4) {
            float4 wv[4];
#pragma unroll
            for (int t = 0; t < 4; ++t)
                wv[t] = ((float4*)Wl[k4 * 4 + t])[j4];
#pragma unroll
            for (int r = 0; r < 4; ++r) {
                float4 xv = ((float4*)xs[g * 4 + r])[kk * 8 + k4];
                acc[r][0] += xv.x * wv[0].x + xv.y * wv[1].x + xv.z * wv[2].x + xv.w * wv[3].x;
                acc[r][1] += xv.x * wv[0].y + xv.y * wv[1].y + xv.z * wv[2].y + xv.w * wv[3].y;
                acc[r][2] += xv.x * wv[0].z + xv.y * wv[1].z + xv.z * wv[2].z + xv.w * wv[3].z;
                acc[r][3] += xv.x * wv[0].w + xv.y * wv[1].w + xv.z * wv[2].w + xv.w * wv[3].w;
            }
        }
    }
#pragma unroll
    for (int r = 0; r < 4; ++r) {
        int gr = row0 + g * 4 + r;
        float dn = dinv[gr];
        __half2 p0 = __floats2half2_rn(acc[r][0] * dn, acc[r][1] * dn);
        __half2 p1 = __floats2half2_rn(acc[r][2] * dn, acc[r][3] * dn);
        union { __half2 h2[2]; float2 f2; } u;
        u.h2[0] = p0; u.h2[1] = p1;
        ((float2*)(h + (size_t)gr * DH))[j4] = u.f2;   // 8B = 4 fp16 feats
    }
}

// ---------------- layer-1 gather-reduce + fused epilogue (r5 proven) --------
__global__ __launch_bounds__(256) void k_agg1(
    const int* __restrict__ offsets, const int* __restrict__ ssrc,
    const __half* __restrict__ h, const float* __restrict__ dinv,
    const float* __restrict__ b1, float* __restrict__ x2)
{
    const int node = blockIdx.x * 4 + (threadIdx.x >> 6);
    const int lane = threadIdx.x & 63;
    const __half2* hp = (const __half2*)h;   // 64 half2 per row
    float2 acc;
    {
        float2 s = __half22float2(hp[(size_t)node * 64 + lane]);  // self-loop
        acc.x = s.x; acc.y = s.y;
    }
    const int begin = offsets[node], end = offsets[node + 1];
    for (int base = begin; base < end; base += 64) {
        const int cnt = min(64, end - base);
        int sv = (base + lane < end) ? ssrc[base + lane] : 0;
        int e = 0;
        for (; e + 8 <= cnt; e += 8) {
            int s0 = __shfl(sv, e),     s1 = __shfl(sv, e + 1);
            int s2 = __shfl(sv, e + 2), s3 = __shfl(sv, e + 3);
            int s4 = __shfl(sv, e + 4), s5 = __shfl(sv, e + 5);
            int s6 = __shfl(sv, e + 6), s7 = __shfl(sv, e + 7);
            float2 v0 = __half22float2(hp[(size_t)s0 * 64 + lane]);
            float2 v1 = __half22float2(hp[(size_t)s1 * 64 + lane]);
            float2 v2 = __half22float2(hp[(size_t)s2 * 64 + lane]);
            float2 v3 = __half22float2(hp[(size_t)s3 * 64 + lane]);
            float2 v4 = __half22float2(hp[(size_t)s4 * 64 + lane]);
            float2 v5 = __half22float2(hp[(size_t)s5 * 64 + lane]);
            float2 v6 = __half22float2(hp[(size_t)s6 * 64 + lane]);
            float2 v7 = __half22float2(hp[(size_t)s7 * 64 + lane]);
            acc.x += ((v0.x + v1.x) + (v2.x + v3.x)) + ((v4.x + v5.x) + (v6.x + v7.x));
            acc.y += ((v0.y + v1.y) + (v2.y + v3.y)) + ((v4.y + v5.y) + (v6.y + v7.y));
        }
        for (; e < cnt; ++e) {
            int s = __shfl(sv, e);
            float2 v = __half22float2(hp[(size_t)s * 64 + lane]);
            acc.x += v.x; acc.y += v.y;
        }
    }
    const float dn = dinv[node];
    float vx = dn * acc.x + b1[2 * lane];
    float vy = dn * acc.y + b1[2 * lane + 1];
    float2 o;
    o.x = vx > 0.f ? vx : 0.f;
    o.y = vy > 0.f ? vy : 0.f;
    ((float2*)x2)[(size_t)node * 64 + lane] = o;
}

// ---------------- layer-2 GEMM:  h2 = dinv * (x2 @ W2), fp32 ----------------
// 32 rows x 64 cols / block, 256 threads; thread = 2 rows x 4 cols.
// LDS 32KB (xs 16KB + 16KB W-half x2 stages) -> 5 blocks/CU, 1250 blocks.
__global__ __launch_bounds__(256) void k_gemm2(
    const float* __restrict__ x2, const float* __restrict__ W,
    const float* __restrict__ dinv, float* __restrict__ h)
{
    __shared__ float xs[32][DH];     // 16 KB
    __shared__ float Wl[64][DOUT];   // 16 KB (one 64-row half of W2)
    const int row0 = blockIdx.x * 32;
    const int j4 = threadIdx.x & 15;   // cols 4*j4 .. 4*j4+3
    const int g  = threadIdx.x >> 4;   // 0..15 -> rows g*2 .. g*2+1

    for (int i = threadIdx.x; i < 32 * 32; i += 256) {
        int r = i >> 5, c4 = i & 31;
        ((float4*)xs[r])[c4] = ((const float4*)(x2 + (size_t)(row0 + r) * DH))[c4];
    }

    float acc[2][4];
#pragma unroll
    for (int r = 0; r < 2; ++r)
#pragma unroll
        for (int c = 0; c < 4; ++c) acc[r][c] = 0.f;

    for (int kk = 0; kk < 2; ++kk) {
        __syncthreads();   // kk=0: also covers xs staging
        for (int i = threadIdx.x; i < 64 * 16; i += 256)
            ((float4*)Wl[i >> 4])[i & 15] =
                ((const float4*)(W + (size_t)kk * 64 * DOUT))[i];
        __syncthreads();
#pragma unroll
        for (int k4 = 0; k4 < 16; ++k4) {
            float4 wv[4];
#pragma unroll
            for (int t = 0; t < 4; ++t)
                wv[t] = ((float4*)Wl[k4 * 4 + t])[j4];
#pragma unroll
            for (int r = 0; r < 2; ++r) {
                float4 xv = ((float4*)xs[g * 2 + r])[kk * 16 + k4];
                acc[r][0] += xv.x * wv[0].x + xv.y * wv[1].x + xv.z * wv[2].x + xv.w * wv[3].x;
                acc[r][1] += xv.x * wv[0].y + xv.y * wv[1].y + xv.z * wv[2].y + xv.w * wv[3].y;
                acc[r][2] += xv.x * wv[0].z + xv.y * wv[1].z + xv.z * wv[2].z + xv.w * wv[3].z;
                acc[r][3] += xv.x * wv[0].w + xv.y * wv[1].w + xv.z * wv[2].w + xv.w * wv[3].w;
            }
        }
    }
#pragma unroll
    for (int r = 0; r < 2; ++r) {
        int gr = row0 + g * 2 + r;
        float dn = dinv[gr];
        float4 o = make_float4(acc[r][0] * dn, acc[r][1] * dn, acc[r][2] * dn, acc[r][3] * dn);
        ((float4*)(h + (size_t)gr * DOUT))[j4] = o;
    }
}

// ---------------- layer-2 gather-reduce, writes final output (r3/r5) --------
__global__ __launch_bounds__(256) void k_agg2(
    const int* __restrict__ offsets, const int* __restrict__ ssrc,
    const float* __restrict__ h, const float* __restrict__ dinv,
    const float* __restrict__ b2, float* __restrict__ out)
{
    const int node = blockIdx.x * 4 + (threadIdx.x >> 6);
    const int lane = threadIdx.x & 63;
    float acc = h[(size_t)node * 64 + lane];      // self-loop term
    const int begin = offsets[node], end = offsets[node + 1];
    for (int base = begin; base < end; base += 64) {
        const int cnt = min(64, end - base);
        int sv = (base + lane < end) ? ssrc[base + lane] : 0;
        int e = 0;
        for (; e + 4 <= cnt; e += 4) {
            int s0 = __shfl(sv, e), s1 = __shfl(sv, e + 1);
            int s2 = __shfl(sv, e + 2), s3 = __shfl(sv, e + 3);
            float v0 = h[(size_t)s0 * 64 + lane];
            float v1 = h[(size_t)s1 * 64 + lane];
            float v2 = h[(size_t)s2 * 64 + lane];
            float v3 = h[(size_t)s3 * 64 + lane];
            acc += (v0 + v1) + (v2 + v3);
        }
        for (; e < cnt; ++e) {
            int s = __shfl(sv, e);
            acc += h[(size_t)s * 64 + lane];
        }
    }
    out[(size_t)node * 64 + lane] = dinv[node] * acc + b2[lane];
}

extern "C" void kernel_launch(void* const* d_in, const int* in_sizes, int n_in,
                              void* d_out, int out_size, void* d_ws, size_t ws_size,
                              hipStream_t stream) {
    const float* x  = (const float*)d_in[0];
    const int*   ei = (const int*)d_in[1];   // [2, E] int32
    const float* W1 = (const float*)d_in[2];
    const float* b1 = (const float*)d_in[3];
    const float* W2 = (const float*)d_in[4];
    const float* b2 = (const float*)d_in[5];
    float* out = (float*)d_out;

    const int n = N_NODES, E = NEDGES;
    const int* src = ei;
    const int* dst = ei + E;

    // Workspace layout (bytes), ~44.2 MB:
    char* ws = (char*)d_ws;
    int*    deg     = (int*)(ws + 0);          // 160000
    int*    bsum    = (int*)(ws + 160000);     // 160 (padding of deg slot)
    int*    offsets = (int*)(ws + 163840);     // 160004
    int*    cursor  = (int*)(ws + 327680);     // 160000
    float*  dinv    = (float*)(ws + 491520);   // 160000
    int*    ssrc    = (int*)(ws + 655360);     // 2560000
    __half* h1      = (__half*)(ws + 3215360); // 10.24MB fp16 table
    float*  h2      = (float*)(ws + 13455360); // 10.24MB fp32
    float*  x2      = (float*)(ws + 23695360); // 20.48MB

    k_deg_init  <<<(n + 255) / 256, 256, 0, stream>>>(deg, n);
    k_deg_accum <<<(E + 255) / 256, 256, 0, stream>>>(dst, deg, E);
    k_scan_local<<<SCAN_BLOCKS, 1024, 0, stream>>>(deg, offsets, bsum, n);
    k_scan_bsum <<<1, 64, 0, stream>>>(bsum);
    k_scan_apply<<<SCAN_BLOCKS, 1024, 0, stream>>>(deg, offsets, bsum, cursor, dinv, n);
    k_bucket    <<<(E + 255) / 256, 256, 0, stream>>>(src, dst, cursor, ssrc, E);

    k_gemm1     <<<n / 32, 256, 0, stream>>>(x, W1, dinv, h1);
    k_agg1      <<<n / 4,  256, 0, stream>>>(offsets, ssrc, h1, dinv, b1, x2);

    k_gemm2     <<<n / 32, 256, 0, stream>>>(x2, W2, dinv, h2);
    k_agg2      <<<n / 4,  256, 0, stream>>>(offsets, ssrc, h2, dinv, b2, out);
}

// Round 7
// 223.686 us; speedup vs baseline: 2.6052x; 1.0489x over previous
//
#include <hip/hip_runtime.h>
#include <hip/hip_fp16.h>

// ClassicalGCN: 2-layer GCN, N=40000, E=640000, 128 -> 128(relu) -> 64, f32.
// Round 7:
//  - gemm1 -> MFMA fp16 (16x16x32, fp32 accum): wave = 16 rows x 128 cols,
//    A converted in-register from fp32 x, B from pre-transposed fp16 WT1.
//  - h2 stored fp16 -> agg2 gather bytes halve (same lever as r5 agg1).
//  - WT1 build merged into deg-init kernel (no extra launch).
// Everything else is the r6-proven version.

#define N_NODES 40000
#define DIN 128
#define DH 128
#define DOUT 64
#define NEDGES 640000
#define SCAN_BLOCKS 40   // ceil(N / 1024)

typedef _Float16 f16x8 __attribute__((ext_vector_type(8)));
typedef float f32x4 __attribute__((ext_vector_type(4)));

// ---------------- init: zero deg + build WT1[n][k] = fp16(W1[k][n]) ---------
__global__ void k_init(int* __restrict__ deg, const float* __restrict__ W,
                       _Float16* __restrict__ WT, int n) {
    int i = blockIdx.x * 256 + threadIdx.x;
    if (i < n) deg[i] = 0;
    if (i < DIN * DH) {
        int k = i >> 7, nn = i & 127;          // W row-major [k][n]
        WT[(size_t)nn * DIN + k] = (_Float16)W[i];
    }
}

__global__ void k_deg_accum(const int* __restrict__ dst, int* __restrict__ deg, int E) {
    int e = blockIdx.x * 256 + threadIdx.x;
    if (e < E) atomicAdd(&deg[dst[e]], 1);
}

// Per-block inclusive scan (1024 elems/block): wave shfl-scan + wave-sum combine.
__global__ __launch_bounds__(1024) void k_scan_local(
    const int* __restrict__ deg, int* __restrict__ offsets,
    int* __restrict__ bsum, int n)
{
    const int i = blockIdx.x * 1024 + threadIdx.x;
    const int lane = threadIdx.x & 63, wid = threadIdx.x >> 6;
    int v = (i < n) ? deg[i] : 0;
    int s = v;
#pragma unroll
    for (int off = 1; off < 64; off <<= 1) {
        int t = __shfl_up(s, off);
        if (lane >= off) s += t;
    }
    __shared__ int wsum[16];
    if (lane == 63) wsum[wid] = s;
    __syncthreads();
    if (threadIdx.x < 16) {
        int ws = wsum[threadIdx.x];
#pragma unroll
        for (int off = 1; off < 16; off <<= 1) {
            int t = __shfl_up(ws, off);
            if (threadIdx.x >= off) ws += t;
        }
        wsum[threadIdx.x] = ws;
    }
    __syncthreads();
    int incl = s + (wid > 0 ? wsum[wid - 1] : 0);
    if (i < n) offsets[i + 1] = incl;
    if (threadIdx.x == 1023) bsum[blockIdx.x] = incl;
}

// One wave: exclusive scan of SCAN_BLOCKS block totals, in place.
__global__ void k_scan_bsum(int* __restrict__ bsum) {
    int lane = threadIdx.x;
    int v = (lane < SCAN_BLOCKS) ? bsum[lane] : 0;
    int s = v;
#pragma unroll
    for (int off = 1; off < 64; off <<= 1) {
        int t = __shfl_up(s, off);
        if (lane >= off) s += t;
    }
    if (lane < SCAN_BLOCKS) bsum[lane] = s - v;
}

// Add block base; emit offsets / cursor / dinv.
__global__ __launch_bounds__(1024) void k_scan_apply(
    const int* __restrict__ deg, int* __restrict__ offsets,
    const int* __restrict__ bsum, int* __restrict__ cursor,
    float* __restrict__ dinv, int n)
{
    const int i = blockIdx.x * 1024 + threadIdx.x;
    if (i == 0) offsets[0] = 0;
    if (i < n) {
        int incl = offsets[i + 1] + bsum[blockIdx.x];
        offsets[i + 1] = incl;
        int d = deg[i];
        cursor[i] = incl - d;
        dinv[i] = rsqrtf((float)(d + 1));   // +1 self-loop
    }
}

// Sort edge srcs into dst-buckets.
__global__ void k_bucket(const int* __restrict__ src, const int* __restrict__ dst,
                         int* __restrict__ cursor, int* __restrict__ ssrc, int E) {
    int e = blockIdx.x * 256 + threadIdx.x;
    if (e < E) {
        int d = dst[e];
        int p = atomicAdd(&cursor[d], 1);
        ssrc[p] = src[e];
    }
}

// ---------------- layer-1 GEMM (MFMA fp16): h1 = fp16(dinv * (x @ W1)) ------
// One wave = 16 rows x 128 cols, K=128 in 4 mfma_f32_16x16x32_f16 steps.
// a_frag: A[m=lane&15][k=quad*8+j] (fp32 x, converted in-register).
// b_frag: B[k][n] = WT1[n=lane&15 of col tile][k contiguous 16B].
// D: col=lane&15, row=quad*4+r (verified m89/m91 mapping).
__global__ __launch_bounds__(256) void k_gemm1(
    const float* __restrict__ x, const _Float16* __restrict__ WT,
    const float* __restrict__ dinv, __half* __restrict__ h)
{
    const int wave = blockIdx.x * 4 + (threadIdx.x >> 6);   // 0..2499
    const int lane = threadIdx.x & 63;
    const int m = lane & 15, quad = lane >> 4;

    f32x4 acc[8];
#pragma unroll
    for (int nt = 0; nt < 8; ++nt) acc[nt] = (f32x4){0.f, 0.f, 0.f, 0.f};

    const float* xrow = x + (size_t)(wave * 16 + m) * DIN + quad * 8;
#pragma unroll
    for (int ks = 0; ks < 4; ++ks) {
        float4 xa = *(const float4*)(xrow + ks * 32);
        float4 xb = *(const float4*)(xrow + ks * 32 + 4);
        f16x8 a = { (_Float16)xa.x, (_Float16)xa.y, (_Float16)xa.z, (_Float16)xa.w,
                    (_Float16)xb.x, (_Float16)xb.y, (_Float16)xb.z, (_Float16)xb.w };
#pragma unroll
        for (int nt = 0; nt < 8; ++nt) {
            f16x8 b = *(const f16x8*)(WT + (size_t)(nt * 16 + m) * DIN + ks * 32 + quad * 8);
            acc[nt] = __builtin_amdgcn_mfma_f32_16x16x32_f16(a, b, acc[nt], 0, 0, 0);
        }
    }
#pragma unroll
    for (int r = 0; r < 4; ++r) {
        int orow = wave * 16 + quad * 4 + r;
        float dn = dinv[orow];
#pragma unroll
        for (int nt = 0; nt < 8; ++nt)
            h[(size_t)orow * DH + nt * 16 + m] = (__half)(acc[nt][r] * dn);
    }
}

// ---------------- layer-1 gather-reduce + fused epilogue (r5 proven) --------
__global__ __launch_bounds__(256) void k_agg1(
    const int* __restrict__ offsets, const int* __restrict__ ssrc,
    const __half* __restrict__ h, const float* __restrict__ dinv,
    const float* __restrict__ b1, float* __restrict__ x2)
{
    const int node = blockIdx.x * 4 + (threadIdx.x >> 6);
    const int lane = threadIdx.x & 63;
    const __half2* hp = (const __half2*)h;   // 64 half2 per row
    float2 acc;
    {
        float2 s = __half22float2(hp[(size_t)node * 64 + lane]);  // self-loop
        acc.x = s.x; acc.y = s.y;
    }
    const int begin = offsets[node], end = offsets[node + 1];
    for (int base = begin; base < end; base += 64) {
        const int cnt = min(64, end - base);
        int sv = (base + lane < end) ? ssrc[base + lane] : 0;
        int e = 0;
        for (; e + 8 <= cnt; e += 8) {
            int s0 = __shfl(sv, e),     s1 = __shfl(sv, e + 1);
            int s2 = __shfl(sv, e + 2), s3 = __shfl(sv, e + 3);
            int s4 = __shfl(sv, e + 4), s5 = __shfl(sv, e + 5);
            int s6 = __shfl(sv, e + 6), s7 = __shfl(sv, e + 7);
            float2 v0 = __half22float2(hp[(size_t)s0 * 64 + lane]);
            float2 v1 = __half22float2(hp[(size_t)s1 * 64 + lane]);
            float2 v2 = __half22float2(hp[(size_t)s2 * 64 + lane]);
            float2 v3 = __half22float2(hp[(size_t)s3 * 64 + lane]);
            float2 v4 = __half22float2(hp[(size_t)s4 * 64 + lane]);
            float2 v5 = __half22float2(hp[(size_t)s5 * 64 + lane]);
            float2 v6 = __half22float2(hp[(size_t)s6 * 64 + lane]);
            float2 v7 = __half22float2(hp[(size_t)s7 * 64 + lane]);
            acc.x += ((v0.x + v1.x) + (v2.x + v3.x)) + ((v4.x + v5.x) + (v6.x + v7.x));
            acc.y += ((v0.y + v1.y) + (v2.y + v3.y)) + ((v4.y + v5.y) + (v6.y + v7.y));
        }
        for (; e < cnt; ++e) {
            int s = __shfl(sv, e);
            float2 v = __half22float2(hp[(size_t)s * 64 + lane]);
            acc.x += v.x; acc.y += v.y;
        }
    }
    const float dn = dinv[node];
    float vx = dn * acc.x + b1[2 * lane];
    float vy = dn * acc.y + b1[2 * lane + 1];
    float2 o;
    o.x = vx > 0.f ? vx : 0.f;
    o.y = vy > 0.f ? vy : 0.f;
    ((float2*)x2)[(size_t)node * 64 + lane] = o;
}

// ---------------- layer-2 GEMM:  h2 = fp16( dinv * (x2 @ W2) ) --------------
// r6 structure (32-row tile, 32KB LDS, 5 blocks/CU); only the store is fp16.
__global__ __launch_bounds__(256) void k_gemm2(
    const float* __restrict__ x2, const float* __restrict__ W,
    const float* __restrict__ dinv, __half* __restrict__ h)
{
    __shared__ float xs[32][DH];     // 16 KB
    __shared__ float Wl[64][DOUT];   // 16 KB (one 64-row half of W2)
    const int row0 = blockIdx.x * 32;
    const int j4 = threadIdx.x & 15;   // cols 4*j4 .. 4*j4+3
    const int g  = threadIdx.x >> 4;   // 0..15 -> rows g*2 .. g*2+1

    for (int i = threadIdx.x; i < 32 * 32; i += 256) {
        int r = i >> 5, c4 = i & 31;
        ((float4*)xs[r])[c4] = ((const float4*)(x2 + (size_t)(row0 + r) * DH))[c4];
    }

    float acc[2][4];
#pragma unroll
    for (int r = 0; r < 2; ++r)
#pragma unroll
        for (int c = 0; c < 4; ++c) acc[r][c] = 0.f;

    for (int kk = 0; kk < 2; ++kk) {
        __syncthreads();   // kk=0: also covers xs staging
        for (int i = threadIdx.x; i < 64 * 16; i += 256)
            ((float4*)Wl[i >> 4])[i & 15] =
                ((const float4*)(W + (size_t)kk * 64 * DOUT))[i];
        __syncthreads();
#pragma unroll
        for (int k4 = 0; k4 < 16; ++k4) {
            float4 wv[4];
#pragma unroll
            for (int t = 0; t < 4; ++t)
                wv[t] = ((float4*)Wl[k4 * 4 + t])[j4];
#pragma unroll
            for (int r = 0; r < 2; ++r) {
                float4 xv = ((float4*)xs[g * 2 + r])[kk * 16 + k4];
                acc[r][0] += xv.x * wv[0].x + xv.y * wv[1].x + xv.z * wv[2].x + xv.w * wv[3].x;
                acc[r][1] += xv.x * wv[0].y + xv.y * wv[1].y + xv.z * wv[2].y + xv.w * wv[3].y;
                acc[r][2] += xv.x * wv[0].z + xv.y * wv[1].z + xv.z * wv[2].z + xv.w * wv[3].z;
                acc[r][3] += xv.x * wv[0].w + xv.y * wv[1].w + xv.z * wv[2].w + xv.w * wv[3].w;
            }
        }
    }
#pragma unroll
    for (int r = 0; r < 2; ++r) {
        int gr = row0 + g * 2 + r;
        float dn = dinv[gr];
        __half2 p0 = __floats2half2_rn(acc[r][0] * dn, acc[r][1] * dn);
        __half2 p1 = __floats2half2_rn(acc[r][2] * dn, acc[r][3] * dn);
        union { __half2 h2[2]; float2 f2; } u;
        u.h2[0] = p0; u.h2[1] = p1;
        ((float2*)(h + (size_t)gr * DOUT))[j4] = u.f2;   // 8B = 4 fp16 feats
    }
}

// ---------------- layer-2 gather-reduce (fp16 table), writes d_out ----------
__global__ __launch_bounds__(256) void k_agg2(
    const int* __restrict__ offsets, const int* __restrict__ ssrc,
    const __half* __restrict__ h, const float* __restrict__ dinv,
    const float* __restrict__ b2, float* __restrict__ out)
{
    const int node = blockIdx.x * 4 + (threadIdx.x >> 6);
    const int lane = threadIdx.x & 63;
    float acc = (float)h[(size_t)node * 64 + lane];   // self-loop term
    const int begin = offsets[node], end = offsets[node + 1];
    for (int base = begin; base < end; base += 64) {
        const int cnt = min(64, end - base);
        int sv = (base + lane < end) ? ssrc[base + lane] : 0;
        int e = 0;
        for (; e + 8 <= cnt; e += 8) {
            int s0 = __shfl(sv, e),     s1 = __shfl(sv, e + 1);
            int s2 = __shfl(sv, e + 2), s3 = __shfl(sv, e + 3);
            int s4 = __shfl(sv, e + 4), s5 = __shfl(sv, e + 5);
            int s6 = __shfl(sv, e + 6), s7 = __shfl(sv, e + 7);
            float v0 = (float)h[(size_t)s0 * 64 + lane];
            float v1 = (float)h[(size_t)s1 * 64 + lane];
            float v2 = (float)h[(size_t)s2 * 64 + lane];
            float v3 = (float)h[(size_t)s3 * 64 + lane];
            float v4 = (float)h[(size_t)s4 * 64 + lane];
            float v5 = (float)h[(size_t)s5 * 64 + lane];
            float v6 = (float)h[(size_t)s6 * 64 + lane];
            float v7 = (float)h[(size_t)s7 * 64 + lane];
            acc += ((v0 + v1) + (v2 + v3)) + ((v4 + v5) + (v6 + v7));
        }
        for (; e < cnt; ++e) {
            int s = __shfl(sv, e);
            acc += (float)h[(size_t)s * 64 + lane];
        }
    }
    out[(size_t)node * 64 + lane] = dinv[node] * acc + b2[lane];
}

extern "C" void kernel_launch(void* const* d_in, const int* in_sizes, int n_in,
                              void* d_out, int out_size, void* d_ws, size_t ws_size,
                              hipStream_t stream) {
    const float* x  = (const float*)d_in[0];
    const int*   ei = (const int*)d_in[1];   // [2, E] int32
    const float* W1 = (const float*)d_in[2];
    const float* b1 = (const float*)d_in[3];
    const float* W2 = (const float*)d_in[4];
    const float* b2 = (const float*)d_in[5];
    float* out = (float*)d_out;

    const int n = N_NODES, E = NEDGES;
    const int* src = ei;
    const int* dst = ei + E;

    // Workspace layout (bytes), ~39.1 MB, all 16B-aligned:
    char* ws = (char*)d_ws;
    int*      deg     = (int*)(ws + 0);           // 160000
    int*      bsum    = (int*)(ws + 160000);      // 160 (padding of deg slot)
    int*      offsets = (int*)(ws + 163840);      // 160004
    int*      cursor  = (int*)(ws + 327680);      // 160000
    float*    dinv    = (float*)(ws + 491520);    // 160000
    int*      ssrc    = (int*)(ws + 655360);      // 2560000
    _Float16* WT1     = (_Float16*)(ws + 3215360);// 32768 fp16 W1^T
    __half*   h1      = (__half*)(ws + 3248128);  // 10.24MB fp16
    __half*   h2      = (__half*)(ws + 13488128); // 5.12MB fp16
    float*    x2      = (float*)(ws + 18608128);  // 20.48MB fp32

    k_init      <<<(n + 255) / 256, 256, 0, stream>>>(deg, W1, WT1, n);
    k_deg_accum <<<(E + 255) / 256, 256, 0, stream>>>(dst, deg, E);
    k_scan_local<<<SCAN_BLOCKS, 1024, 0, stream>>>(deg, offsets, bsum, n);
    k_scan_bsum <<<1, 64, 0, stream>>>(bsum);
    k_scan_apply<<<SCAN_BLOCKS, 1024, 0, stream>>>(deg, offsets, bsum, cursor, dinv, n);
    k_bucket    <<<(E + 255) / 256, 256, 0, stream>>>(src, dst, cursor, ssrc, E);

    k_gemm1     <<<n / 64, 256, 0, stream>>>(x, WT1, dinv, h1);    // 625 blocks, 4 waves/block
    k_agg1      <<<n / 4,  256, 0, stream>>>(offsets, ssrc, h1, dinv, b1, x2);

    k_gemm2     <<<n / 32, 256, 0, stream>>>(x2, W2, dinv, h2);
    k_agg2      <<<n / 4,  256, 0, stream>>>(offsets, ssrc, h2, dinv, b2, out);
}

// Round 8
// 214.497 us; speedup vs baseline: 2.7168x; 1.0428x over previous
//
#include <hip/hip_runtime.h>
#include <hip/hip_fp16.h>

// ClassicalGCN: 2-layer GCN, N=40000, E=640000, 128 -> 128(relu) -> 64, f32.
// Round 8:
//  - x2 stored fp16; gemm2 -> MFMA fp16 reading x2 directly (no LDS), W2T in
//    k_init. Saves ~20MB round-trip + moves gemm2 to matrix pipe.
//  - scan_bsum folded into scan_apply (one fewer launch).
//  - deg_accum/bucket read edges as int4 (4 edges/thread).

#define N_NODES 40000
#define DIN 128
#define DH 128
#define DOUT 64
#define NEDGES 640000
#define SCAN_BLOCKS 40   // ceil(N / 1024)

typedef _Float16 f16x8 __attribute__((ext_vector_type(8)));
typedef float f32x4 __attribute__((ext_vector_type(4)));

// ------ init: zero deg + build WT1[n][k]=fp16(W1[k][n]), WT2[n][k]=fp16(W2[k][n])
__global__ void k_init(int* __restrict__ deg, const float* __restrict__ W1,
                       const float* __restrict__ W2,
                       _Float16* __restrict__ WT1, _Float16* __restrict__ WT2, int n) {
    int i = blockIdx.x * 256 + threadIdx.x;
    if (i < n) deg[i] = 0;
    if (i < DIN * DH) {
        int k = i >> 7, nn = i & 127;            // W1 row-major [k][n], n=128
        WT1[(size_t)nn * DIN + k] = (_Float16)W1[i];
    }
    if (i < DH * DOUT) {
        int k = i >> 6, nn = i & 63;             // W2 row-major [k][n], n=64
        WT2[(size_t)nn * DH + k] = (_Float16)W2[i];
    }
}

// 4 edges/thread (int4).
__global__ void k_deg_accum(const int4* __restrict__ dst4, int* __restrict__ deg, int E4) {
    int e = blockIdx.x * 256 + threadIdx.x;
    if (e < E4) {
        int4 d = dst4[e];
        atomicAdd(&deg[d.x], 1); atomicAdd(&deg[d.y], 1);
        atomicAdd(&deg[d.z], 1); atomicAdd(&deg[d.w], 1);
    }
}

// Per-block inclusive scan (1024 elems/block): wave shfl-scan + wave-sum combine.
__global__ __launch_bounds__(1024) void k_scan_local(
    const int* __restrict__ deg, int* __restrict__ offsets,
    int* __restrict__ bsum, int n)
{
    const int i = blockIdx.x * 1024 + threadIdx.x;
    const int lane = threadIdx.x & 63, wid = threadIdx.x >> 6;
    int v = (i < n) ? deg[i] : 0;
    int s = v;
#pragma unroll
    for (int off = 1; off < 64; off <<= 1) {
        int t = __shfl_up(s, off);
        if (lane >= off) s += t;
    }
    __shared__ int wsum[16];
    if (lane == 63) wsum[wid] = s;
    __syncthreads();
    if (threadIdx.x < 16) {
        int ws = wsum[threadIdx.x];
#pragma unroll
        for (int off = 1; off < 16; off <<= 1) {
            int t = __shfl_up(ws, off);
            if (threadIdx.x >= off) ws += t;
        }
        wsum[threadIdx.x] = ws;
    }
    __syncthreads();
    int incl = s + (wid > 0 ? wsum[wid - 1] : 0);
    if (i < n) offsets[i + 1] = incl;
    if (threadIdx.x == 1023) bsum[blockIdx.x] = incl;   // block total
}

// Add block base (computed in-kernel from bsum); emit offsets / cursor / dinv.
__global__ __launch_bounds__(1024) void k_scan_apply(
    const int* __restrict__ deg, int* __restrict__ offsets,
    const int* __restrict__ bsum, int* __restrict__ cursor,
    float* __restrict__ dinv, int n)
{
    __shared__ int base_s;
    if (threadIdx.x < 64) {
        int t = threadIdx.x;
        int bv = (t < SCAN_BLOCKS && t < blockIdx.x) ? bsum[t] : 0;
#pragma unroll
        for (int off = 32; off > 0; off >>= 1) bv += __shfl_down(bv, off);
        if (t == 0) base_s = bv;
    }
    __syncthreads();
    const int base = base_s;
    const int i = blockIdx.x * 1024 + threadIdx.x;
    if (i == 0) offsets[0] = 0;
    if (i < n) {
        int incl = offsets[i + 1] + base;
        offsets[i + 1] = incl;
        int d = deg[i];
        cursor[i] = incl - d;
        dinv[i] = rsqrtf((float)(d + 1));   // +1 self-loop
    }
}

// Sort edge srcs into dst-buckets; 4 edges/thread.
__global__ void k_bucket(const int4* __restrict__ src4, const int4* __restrict__ dst4,
                         int* __restrict__ cursor, int* __restrict__ ssrc, int E4) {
    int e = blockIdx.x * 256 + threadIdx.x;
    if (e < E4) {
        int4 s = src4[e];
        int4 d = dst4[e];
        ssrc[atomicAdd(&cursor[d.x], 1)] = s.x;
        ssrc[atomicAdd(&cursor[d.y], 1)] = s.y;
        ssrc[atomicAdd(&cursor[d.z], 1)] = s.z;
        ssrc[atomicAdd(&cursor[d.w], 1)] = s.w;
    }
}

// ---------------- layer-1 GEMM (MFMA fp16): h1 = fp16(dinv * (x @ W1)) ------
// One wave = 16 rows x 128 cols, K=128 in 4 mfma_f32_16x16x32_f16 steps.
__global__ __launch_bounds__(256) void k_gemm1(
    const float* __restrict__ x, const _Float16* __restrict__ WT,
    const float* __restrict__ dinv, __half* __restrict__ h)
{
    const int wave = blockIdx.x * 4 + (threadIdx.x >> 6);   // 0..2499
    const int lane = threadIdx.x & 63;
    const int m = lane & 15, quad = lane >> 4;

    f32x4 acc[8];
#pragma unroll
    for (int nt = 0; nt < 8; ++nt) acc[nt] = (f32x4){0.f, 0.f, 0.f, 0.f};

    const float* xrow = x + (size_t)(wave * 16 + m) * DIN + quad * 8;
#pragma unroll
    for (int ks = 0; ks < 4; ++ks) {
        float4 xa = *(const float4*)(xrow + ks * 32);
        float4 xb = *(const float4*)(xrow + ks * 32 + 4);
        f16x8 a = { (_Float16)xa.x, (_Float16)xa.y, (_Float16)xa.z, (_Float16)xa.w,
                    (_Float16)xb.x, (_Float16)xb.y, (_Float16)xb.z, (_Float16)xb.w };
#pragma unroll
        for (int nt = 0; nt < 8; ++nt) {
            f16x8 b = *(const f16x8*)(WT + (size_t)(nt * 16 + m) * DIN + ks * 32 + quad * 8);
            acc[nt] = __builtin_amdgcn_mfma_f32_16x16x32_f16(a, b, acc[nt], 0, 0, 0);
        }
    }
#pragma unroll
    for (int r = 0; r < 4; ++r) {
        int orow = wave * 16 + quad * 4 + r;
        float dn = dinv[orow];
#pragma unroll
        for (int nt = 0; nt < 8; ++nt)
            h[(size_t)orow * DH + nt * 16 + m] = (__half)(acc[nt][r] * dn);
    }
}

// ---------------- layer-1 gather-reduce + fused epilogue; writes fp16 x2 ----
__global__ __launch_bounds__(256) void k_agg1(
    const int* __restrict__ offsets, const int* __restrict__ ssrc,
    const __half* __restrict__ h, const float* __restrict__ dinv,
    const float* __restrict__ b1, __half* __restrict__ x2)
{
    const int node = blockIdx.x * 4 + (threadIdx.x >> 6);
    const int lane = threadIdx.x & 63;
    const __half2* hp = (const __half2*)h;   // 64 half2 per row
    float2 acc;
    {
        float2 s = __half22float2(hp[(size_t)node * 64 + lane]);  // self-loop
        acc.x = s.x; acc.y = s.y;
    }
    const int begin = offsets[node], end = offsets[node + 1];
    for (int base = begin; base < end; base += 64) {
        const int cnt = min(64, end - base);
        int sv = (base + lane < end) ? ssrc[base + lane] : 0;
        int e = 0;
        for (; e + 8 <= cnt; e += 8) {
            int s0 = __shfl(sv, e),     s1 = __shfl(sv, e + 1);
            int s2 = __shfl(sv, e + 2), s3 = __shfl(sv, e + 3);
            int s4 = __shfl(sv, e + 4), s5 = __shfl(sv, e + 5);
            int s6 = __shfl(sv, e + 6), s7 = __shfl(sv, e + 7);
            float2 v0 = __half22float2(hp[(size_t)s0 * 64 + lane]);
            float2 v1 = __half22float2(hp[(size_t)s1 * 64 + lane]);
            float2 v2 = __half22float2(hp[(size_t)s2 * 64 + lane]);
            float2 v3 = __half22float2(hp[(size_t)s3 * 64 + lane]);
            float2 v4 = __half22float2(hp[(size_t)s4 * 64 + lane]);
            float2 v5 = __half22float2(hp[(size_t)s5 * 64 + lane]);
            float2 v6 = __half22float2(hp[(size_t)s6 * 64 + lane]);
            float2 v7 = __half22float2(hp[(size_t)s7 * 64 + lane]);
            acc.x += ((v0.x + v1.x) + (v2.x + v3.x)) + ((v4.x + v5.x) + (v6.x + v7.x));
            acc.y += ((v0.y + v1.y) + (v2.y + v3.y)) + ((v4.y + v5.y) + (v6.y + v7.y));
        }
        for (; e < cnt; ++e) {
            int s = __shfl(sv, e);
            float2 v = __half22float2(hp[(size_t)s * 64 + lane]);
            acc.x += v.x; acc.y += v.y;
        }
    }
    const float dn = dinv[node];
    float vx = dn * acc.x + b1[2 * lane];
    float vy = dn * acc.y + b1[2 * lane + 1];
    __half2 o = __floats2half2_rn(vx > 0.f ? vx : 0.f, vy > 0.f ? vy : 0.f);
    ((__half2*)x2)[(size_t)node * 64 + lane] = o;
}

// ---------------- layer-2 GEMM (MFMA fp16): h2 = fp16(dinv * (x2 @ W2)) -----
// One wave = 16 rows x 64 cols, K=128; A read directly from fp16 x2.
__global__ __launch_bounds__(256) void k_gemm2(
    const __half* __restrict__ x2, const _Float16* __restrict__ WT,
    const float* __restrict__ dinv, __half* __restrict__ h)
{
    const int wave = blockIdx.x * 4 + (threadIdx.x >> 6);   // 0..2499
    const int lane = threadIdx.x & 63;
    const int m = lane & 15, quad = lane >> 4;

    f32x4 acc[4];
#pragma unroll
    for (int nt = 0; nt < 4; ++nt) acc[nt] = (f32x4){0.f, 0.f, 0.f, 0.f};

    const _Float16* xrow = (const _Float16*)x2 + (size_t)(wave * 16 + m) * DH + quad * 8;
#pragma unroll
    for (int ks = 0; ks < 4; ++ks) {
        f16x8 a = *(const f16x8*)(xrow + ks * 32);
#pragma unroll
        for (int nt = 0; nt < 4; ++nt) {
            f16x8 b = *(const f16x8*)(WT + (size_t)(nt * 16 + m) * DH + ks * 32 + quad * 8);
            acc[nt] = __builtin_amdgcn_mfma_f32_16x16x32_f16(a, b, acc[nt], 0, 0, 0);
        }
    }
#pragma unroll
    for (int r = 0; r < 4; ++r) {
        int orow = wave * 16 + quad * 4 + r;
        float dn = dinv[orow];
#pragma unroll
        for (int nt = 0; nt < 4; ++nt)
            h[(size_t)orow * DOUT + nt * 16 + m] = (__half)(acc[nt][r] * dn);
    }
}

// ---------------- layer-2 gather-reduce (fp16 table), writes d_out ----------
__global__ __launch_bounds__(256) void k_agg2(
    const int* __restrict__ offsets, const int* __restrict__ ssrc,
    const __half* __restrict__ h, const float* __restrict__ dinv,
    const float* __restrict__ b2, float* __restrict__ out)
{
    const int node = blockIdx.x * 4 + (threadIdx.x >> 6);
    const int lane = threadIdx.x & 63;
    float acc = (float)h[(size_t)node * 64 + lane];   // self-loop term
    const int begin = offsets[node], end = offsets[node + 1];
    for (int base = begin; base < end; base += 64) {
        const int cnt = min(64, end - base);
        int sv = (base + lane < end) ? ssrc[base + lane] : 0;
        int e = 0;
        for (; e + 8 <= cnt; e += 8) {
            int s0 = __shfl(sv, e),     s1 = __shfl(sv, e + 1);
            int s2 = __shfl(sv, e + 2), s3 = __shfl(sv, e + 3);
            int s4 = __shfl(sv, e + 4), s5 = __shfl(sv, e + 5);
            int s6 = __shfl(sv, e + 6), s7 = __shfl(sv, e + 7);
            float v0 = (float)h[(size_t)s0 * 64 + lane];
            float v1 = (float)h[(size_t)s1 * 64 + lane];
            float v2 = (float)h[(size_t)s2 * 64 + lane];
            float v3 = (float)h[(size_t)s3 * 64 + lane];
            float v4 = (float)h[(size_t)s4 * 64 + lane];
            float v5 = (float)h[(size_t)s5 * 64 + lane];
            float v6 = (float)h[(size_t)s6 * 64 + lane];
            float v7 = (float)h[(size_t)s7 * 64 + lane];
            acc += ((v0 + v1) + (v2 + v3)) + ((v4 + v5) + (v6 + v7));
        }
        for (; e < cnt; ++e) {
            int s = __shfl(sv, e);
            acc += (float)h[(size_t)s * 64 + lane];
        }
    }
    out[(size_t)node * 64 + lane] = dinv[node] * acc + b2[lane];
}

extern "C" void kernel_launch(void* const* d_in, const int* in_sizes, int n_in,
                              void* d_out, int out_size, void* d_ws, size_t ws_size,
                              hipStream_t stream) {
    const float* x  = (const float*)d_in[0];
    const int*   ei = (const int*)d_in[1];   // [2, E] int32
    const float* W1 = (const float*)d_in[2];
    const float* b1 = (const float*)d_in[3];
    const float* W2 = (const float*)d_in[4];
    const float* b2 = (const float*)d_in[5];
    float* out = (float*)d_out;

    const int n = N_NODES, E = NEDGES;
    const int* src = ei;
    const int* dst = ei + E;

    // Workspace layout (bytes), ~28.9 MB, all 16B-aligned:
    char* ws = (char*)d_ws;
    int*      deg     = (int*)(ws + 0);            // 160000
    int*      bsum    = (int*)(ws + 160000);       // 160 (padding of deg slot)
    int*      offsets = (int*)(ws + 163840);       // 160004
    int*      cursor  = (int*)(ws + 327680);       // 160000
    float*    dinv    = (float*)(ws + 491520);     // 160000
    int*      ssrc    = (int*)(ws + 655360);       // 2560000
    _Float16* WT1     = (_Float16*)(ws + 3215360); // 32768  fp16 W1^T
    _Float16* WT2     = (_Float16*)(ws + 3248128); // 16384  fp16 W2^T
    __half*   h1      = (__half*)(ws + 3264512);   // 10.24MB fp16
    __half*   h2      = (__half*)(ws + 13504512);  // 5.12MB fp16
    __half*   x2      = (__half*)(ws + 18624512);  // 10.24MB fp16

    k_init      <<<(n + 255) / 256, 256, 0, stream>>>(deg, W1, W2, WT1, WT2, n);
    k_deg_accum <<<(E / 4 + 255) / 256, 256, 0, stream>>>((const int4*)dst, deg, E / 4);
    k_scan_local<<<SCAN_BLOCKS, 1024, 0, stream>>>(deg, offsets, bsum, n);
    k_scan_apply<<<SCAN_BLOCKS, 1024, 0, stream>>>(deg, offsets, bsum, cursor, dinv, n);
    k_bucket    <<<(E / 4 + 255) / 256, 256, 0, stream>>>((const int4*)src, (const int4*)dst,
                                                          cursor, ssrc, E / 4);

    k_gemm1     <<<n / 64, 256, 0, stream>>>(x, WT1, dinv, h1);
    k_agg1      <<<n / 4,  256, 0, stream>>>(offsets, ssrc, h1, dinv, b1, x2);

    k_gemm2     <<<n / 64, 256, 0, stream>>>(x2, WT2, dinv, h2);
    k_agg2      <<<n / 4,  256, 0, stream>>>(offsets, ssrc, h2, dinv, b2, out);
}